// Round 6
// baseline (448.509 us; speedup 1.0000x reference)
//
#include <hip/hip_runtime.h>
#include <math.h>

// Closed-form pipeline with Hermitian (real-output) symmetry:
//   Fx  = fft2_128(x), stored cols 0..64 only (x real -> 2D-Hermitian)
//   FBtmp = row FFTs (N=256) of 25 psf rows (k3)
//   k6 fused: per-block on-the-fly column DFT of FBtmp -> 4 FBh rows;
//             M=(1-S1)/(S2+b); FX rows; radix-4 row IFFT (wave-local,
//             barrier-free); Hermitian fold; write Zf[0..127]
//   k7: pure 128-pt C2R column IFFT of Zf (wave-local radix-4)
// R7: j-invariant twiddles -> cooperative LDS twiddle tables everywhere.
// R8: single HB-table serves all Stockham stages; fold moved into k6.
// R9: radix-4 Stockham; k6 wave-owns-row -> no barriers in FFT loop.
// R10: Fx 2D-Hermitian halving; k2/k7 wave-local columns ([col][130] pad).
// R11: FBh round-trip eliminated; k6 computes 4 rows from FBtmp via 25-tap
//   dots; mirror rows from conj/(-1)^p recombination (same products).
// R12: k6 was latency-bound (VALUBusy 78%, occ 37%, LDS 28.7KB -> 5 blk/CU):
//   (a) overlay stage[] onto FFT buf1 and Tt[] onto buf0 (+1 barrier) ->
//       LDS 19.5KB -> 8 blocks/CU (100% wave cap), launch_bounds(256,8);
//   (b) FFT stage 3 (m=64 -> jm=0 -> w=1) peeled twiddle-free, in-place.

static __device__ __forceinline__ float2 cmul(float2 a, float2 b) {
    return make_float2(a.x * b.x - a.y * b.y, a.x * b.y + a.y * b.x);
}
static __device__ __forceinline__ float2 cadd(float2 a, float2 b) {
    return make_float2(a.x + b.x, a.y + b.y);
}
static __device__ __forceinline__ float2 csub(float2 a, float2 b) {
    return make_float2(a.x - b.x, a.y - b.y);
}
static __device__ __forceinline__ float2 conjf2(float2 a) {
    return make_float2(a.x, -a.y);
}
static __device__ __forceinline__ int PHI(int i) { return i + (i >> 3); }

// Fill tw[i] = (cos(SIGN*pi*i/HB), sin(SIGN*pi*i/HB)) for i in [0,HB).
template <int HB, int SIGN, int THREADS>
static __device__ __forceinline__ void fill_tw(float2* tw) {
    for (int i = threadIdx.x; i < HB; i += THREADS) {
        float s, c;
        __sincosf((float)SIGN * (float)M_PI * (float)i / (float)HB, &s, &c);
        tw[i] = make_float2(c, s);
    }
}

// ---------------- radix-2 Stockham rows (k1/k3) ----------------
template <int N, int R, int SIGN>
static __device__ __forceinline__ int fft_lds_rows(float2 (&buf)[2][R][N],
                                                   const float2* __restrict__ tw) {
    constexpr int HB = N / 2;
    const int tid = threadIdx.x;
    const int row = tid / HB;
    const int bt = tid % HB;
    int cur = 0, m = 1;
    for (int l = HB; l >= 1; l >>= 1) {
        __syncthreads();
        const int k = bt & (m - 1);
        const float2 w = tw[bt - k];
        float2 a = buf[cur][row][bt];
        float2 b = buf[cur][row][bt + HB];
        float2 d = make_float2(a.x - b.x, a.y - b.y);
        float2 wd = make_float2(w.x * d.x - w.y * d.y, w.x * d.y + w.y * d.x);
        const int o = 2 * bt - k;
        buf[cur ^ 1][row][o] = make_float2(a.x + b.x, a.y + b.y);
        buf[cur ^ 1][row][o + m] = wd;
        cur ^= 1;
        m <<= 1;
    }
    __syncthreads();
    return cur;
}

// ------------- wave-local mixed radix-4/2 128-pt column FFT -------------
template <int SIGN, int NCOL>
static __device__ __forceinline__ int fft4_cols_wavelocal(float2 (&buf)[2][NCOL][130],
                                                          const float2* __restrict__ tw) {
    const int lane = threadIdx.x & 63;
    const int wv = threadIdx.x >> 6;
    const int col = wv * 4 + (lane >> 4);
    const int r = lane & 15;
    int cur = 0, m = 1;
#pragma unroll
    for (int st = 0; st < 3; ++st) {
#pragma unroll
        for (int b = 0; b < 2; ++b) {
            const int bq = r + 16 * b;
            const int k = bq & (m - 1);
            const int jm = bq - k;
            const float2 w1 = tw[jm];
            const float2 w2 = tw[2 * jm];
            const float2 w3 = tw[3 * jm];
            float2 a0 = buf[cur][col][bq];
            float2 a1 = buf[cur][col][bq + 32];
            float2 a2 = buf[cur][col][bq + 64];
            float2 a3 = buf[cur][col][bq + 96];
            float2 s02 = cadd(a0, a2), d02 = csub(a0, a2);
            float2 s13 = cadd(a1, a3), d13 = csub(a1, a3);
            float2 b0 = cadd(s02, s13), b2 = csub(s02, s13);
            float2 b1 = make_float2(d02.x - (float)SIGN * d13.y,
                                    d02.y + (float)SIGN * d13.x);
            float2 b3 = make_float2(d02.x + (float)SIGN * d13.y,
                                    d02.y - (float)SIGN * d13.x);
            const int o = 4 * jm + k;
            buf[cur ^ 1][col][o] = b0;
            buf[cur ^ 1][col][o + m] = cmul(w1, b1);
            buf[cur ^ 1][col][o + 2 * m] = cmul(w2, b2);
            buf[cur ^ 1][col][o + 3 * m] = cmul(w3, b3);
        }
        cur ^= 1;
        m <<= 2;
    }
#pragma unroll
    for (int b = 0; b < 4; ++b) {  // radix-2 tail, m=64, j=0
        const int bt = r + 16 * b;
        float2 a = buf[cur][col][bt];
        float2 bb = buf[cur][col][bt + 64];
        buf[cur ^ 1][col][bt] = cadd(a, bb);
        buf[cur ^ 1][col][bt + 64] = csub(a, bb);
    }
    return cur ^ 1;
}

// K1: row FFT of x (N=128) with pack-2; write only cols 0..64 (Hermitian).
__global__ __launch_bounds__(256) void k1_fft_rows_x(const float* __restrict__ x,
                                                     float2* __restrict__ Fx) {
    __shared__ float2 buf[2][4][128];
    __shared__ float2 tw64m[64];
    const int tid = threadIdx.x;
    const int row = tid >> 6;   // pair slot 0..3
    const int t = tid & 63;
    fill_tw<64, -1, 256>(tw64m);
    const int gpair = blockIdx.x * 4 + row;  // img*64 + pr
    const float* r0 = x + (size_t)gpair * 256;        // row 2*pr (128 floats)
    const float* r1 = r0 + 128;                       // row 2*pr+1
    const float2 a0 = ((const float2*)r0)[t];
    const float2 a1 = ((const float2*)r1)[t];
    buf[0][row][2 * t].x = a0.x;
    buf[0][row][2 * t].y = a1.x;
    buf[0][row][2 * t + 1].x = a0.y;
    buf[0][row][2 * t + 1].y = a1.y;
    int cur = fft_lds_rows<128, 4, -1>(buf, tw64m);
    float2* d0 = Fx + (size_t)gpair * 256;            // Fx row 2*pr
    float2* d1 = d0 + 128;
    for (int h = 0; h < 2; ++h) {
        int tt = t + h * 64;
        if (tt > 64) continue;  // Hermitian: cols 65..127 reconstructed in k6
        float2 Zt = buf[cur][row][tt];
        float2 Zm = buf[cur][row][(128 - tt) & 127];
        d0[tt] = make_float2(0.5f * (Zt.x + Zm.x), 0.5f * (Zt.y - Zm.y));
        float ax = Zt.x - Zm.x, ay = Zt.y + Zm.y;
        d1[tt] = make_float2(0.5f * ay, -0.5f * ax);
    }
}

// K2: column FFT of Fx, in place, cols 0..64 only -> 5 tiles of 16.
__global__ __launch_bounds__(256) void k2_fft_cols_x(float2* __restrict__ Fx) {
    __shared__ float2 buf[2][16][130];
    __shared__ float2 tw[96];
    const int tid = threadIdx.x;
    const int img = blockIdx.x / 5;
    const int c0 = (blockIdx.x % 5) * 16;
    for (int i = tid; i < 96; i += 256) {
        float s, c;
        __sincosf(-(float)M_PI * (float)i / 64.f, &s, &c);
        tw[i] = make_float2(c, s);
    }
    float2* base = Fx + (size_t)img * 16384 + c0;
    for (int it = 0; it < 8; ++it) {
        int idx = it * 256 + tid;
        int rr = idx >> 4, cc = idx & 15;
        buf[0][cc][rr] = base[rr * 128 + cc];
    }
    __syncthreads();
    int cur = fft4_cols_wavelocal<-1, 16>(buf, tw);
    __syncthreads();
    for (int it = 0; it < 8; ++it) {
        int idx = it * 256 + tid;
        int rr = idx >> 4, cc = idx & 15;
        base[rr * 128 + cc] = buf[cur][cc][rr];
    }
}

// K3: row FFT of padded+rolled psf (N=256), compact output [img][25][256].
__global__ __launch_bounds__(128) void k3_fft_rows_k(const float* __restrict__ kin,
                                                     float2* __restrict__ FBtmp) {
    __shared__ float2 buf[2][1][256];
    __shared__ float2 tw128m[128];
    const int tid = threadIdx.x;  // 128
    const int img = blockIdx.x / 25;
    const int lr = blockIdx.x % 25;
    fill_tw<128, -1, 128>(tw128m);
    const float* krow = kin + img * 625 + lr * 25;
    for (int h = 0; h < 2; ++h) {
        int v = tid + h * 128;
        int pc = (v + 12) & 255;
        buf[0][0][v] = make_float2(pc < 25 ? krow[pc] : 0.f, 0.f);
    }
    int cur = fft_lds_rows<256, 1, -1>(buf, tw128m);
    float2* dst = FBtmp + (size_t)img * 6400 + lr * 256;
    dst[tid] = buf[cur][0][tid];
    dst[tid + 128] = buf[cur][0][tid + 128];
}

// K6: fused column-DFT + M + FX build + radix-4 row IFFT + Hermitian fold.
// Block = (img, p-pair {pa=2b, pb=2b+1}); wave rs owns one of 4 rows.
// LDS overlays (R12): Tt lives in buf0 (consumed before buf0's first write);
// stage lives in buf1 (consumed before FFT st0 writes buf1; extra barrier).
__global__ __launch_bounds__(256, 8) void k6_fused(const float2* __restrict__ FBtmp,
                                                   const float2* __restrict__ Fx,
                                                   const float* __restrict__ alpha,
                                                   float2* __restrict__ Zf) {
    __shared__ float2 sm_buf0[4 * 288];  // FFT ping buffer; first 50 = Tt
    __shared__ float2 sm_buf1[4 * 288];  // FFT pong buffer; first 1024 = stage
    __shared__ float2 tw[192];           // e^{+i pi k/128}, k<192
    float2* Tt = sm_buf0;                // [2][25] flat: which*25+p
    float2* stageF = sm_buf1;            // [4][256] flat: s*256+i
    const int tid = threadIdx.x;
    const int rs = tid >> 6;             // row slot = wave id
    const int q = tid & 63;
    const int img = blockIdx.x / 33;
    const int bq = blockIdx.x % 33;
    const int pa = 2 * bq;
    const int pb = (pa + 1 < 65) ? (pa + 1) : 64;   // last block: pb==pa==64

    // Issue S loads early (coalesced over j=tid; FBtmp slab is L2-resident).
    const float2* src = FBtmp + (size_t)img * 6400 + tid;
    float2 S[25];
#pragma unroll
    for (int p = 0; p < 25; ++p) S[p] = src[p * 256];

    for (int i = tid; i < 192; i += 256) {
        float s, c;
        __sincosf((float)M_PI * (float)i / 128.f, &s, &c);
        tw[i] = make_float2(c, s);
    }
    {  // DFT twiddles: T_u[p] = W_256^{u(p+244)}, W = e^{-2pi i/256}
        const float k2pi = -2.f * (float)M_PI / 256.f;
        for (int i = tid; i < 50; i += 256) {
            const int which = i / 25, p = i - which * 25;
            const int u = which ? pb : pa;
            float s, c;
            __sincosf(k2pi * (float)((u * (p + 244)) & 255), &s, &c);
            Tt[which * 25 + p] = make_float2(c, s);
        }
    }
    __syncthreads();  // BARRIER 0: Tt visible

    // On-the-fly column DFT: 4 rows. Mirror row 128-u via
    //   FBh[128-u][j] = sum_p (-1)^p S[p] conj(T_u[p])  (same 4 products).
    {
        float2 aA = make_float2(0.f, 0.f), bA = make_float2(0.f, 0.f);
        float2 aB = make_float2(0.f, 0.f), bB = make_float2(0.f, 0.f);
#pragma unroll
        for (int p = 0; p < 25; ++p) {
            const float2 s = S[p];
            const float2 ta = Tt[p];
            const float axx = ta.x * s.x, ayy = ta.y * s.y;
            const float axy = ta.x * s.y, ayx = ta.y * s.x;
            aA.x += axx - ayy;
            aA.y += axy + ayx;
            if (p & 1) {
                bA.x -= axx + ayy;
                bA.y -= axy - ayx;
            } else {
                bA.x += axx + ayy;
                bA.y += axy - ayx;
            }
            const float2 tb = Tt[25 + p];
            const float bxx = tb.x * s.x, byy = tb.y * s.y;
            const float bxy = tb.x * s.y, byx = tb.y * s.x;
            aB.x += bxx - byy;
            aB.y += bxy + byx;
            if (p & 1) {
                bB.x -= bxx + byy;
                bB.y -= bxy - byx;
            } else {
                bB.x += bxx + byy;
                bB.y += bxy - byx;
            }
        }
        stageF[tid] = aA;          // FBh[pa]
        stageF[256 + tid] = bA;    // FBh[128-pa]
        stageF[512 + tid] = aB;    // FBh[pb]
        stageF[768 + tid] = bB;    // FBh[128-pb]
    }
    __syncthreads();  // BARRIER 1: stage[] visible (Tt dead; buf0 free)

    const int p = (rs < 2) ? pa : pb;
    const int sb = rs & 2;
    const int u = ((rs & 1) == 0) ? p : (128 - p);   // 0..128
    const int um = u & 127;
    const int msel = (um == p) ? 0 : 1;
    const int mi = sb | msel;
    const int oi = sb | (1 - msel);

    const float ci = tw[um].x, si = -tw[um].y;
    const float b = 1.f / (1.f + __expf(9.f - alpha[img & 63])) + 1e-3f;
    const float scale = 1.f / 65536.f;
    const float2 Di0 = make_float2(1.f + ci, si);
    const float2 Di1 = make_float2(1.f - ci, -si);
    const float2 Du = (u < 128) ? Di0 : Di1;
#pragma unroll
    for (int h = 0; h < 2; ++h) {
        const int t = q + 64 * h;        // 0..127
        float2 f00 = stageF[mi * 256 + t];
        float2 f01 = stageF[mi * 256 + t + 128];
        float2 f10, f11;
        if (um == 0) {  // rows {0,128}: row 128 direct
            f10 = stageF[oi * 256 + t];
            f11 = stageF[oi * 256 + t + 128];
        } else {
            f10 = conjf2(stageF[oi * 256 + ((256 - t) & 255)]);
            f11 = conjf2(stageF[oi * 256 + 128 - t]);
        }
        // Fx stored cols 0..64 only; mirror t>64: conj(Fx[(128-um)%128][128-t])
        const bool mir = (t > 64);
        const int rr = mir ? ((128 - um) & 127) : um;
        const int cc = mir ? (128 - t) : t;
        float2 fx = Fx[(size_t)img * 16384 + rr * 128 + cc];
        if (mir) fx.y = -fx.y;
        const float cj = tw[t].x, sj = -tw[t].y;
        float2 Dj0 = make_float2(1.f + cj, sj);
        float2 Dj1 = make_float2(1.f - cj, -sj);
        // S1 = (f00*Dj0 + f01*Dj1)*Di0 + (f10*Dj0 + f11*Dj1)*Di1  (6 cmuls)
        float2 A = cadd(cmul(f00, Dj0), cmul(f01, Dj1));
        float2 Bt = cadd(cmul(f10, Dj0), cmul(f11, Dj1));
        float2 S1 = cadd(cmul(A, Di0), cmul(Bt, Di1));
        S1.x *= 0.25f;
        S1.y *= 0.25f;
        float S2 = 0.25f * (f00.x * f00.x + f00.y * f00.y + f01.x * f01.x + f01.y * f01.y +
                            f10.x * f10.x + f10.y * f10.y + f11.x * f11.x + f11.y * f11.y);
        float inv = 1.f / (S2 + b);
        float2 mm = make_float2((1.f - S1.x) * inv, (-S1.y) * inv);
        float2 c0v = (u < 128) ? f00 : f10;
        float2 c1v = (u < 128) ? f01 : f10;
        c1v = (u < 128) ? f01 : f11;
        float2 t0 = cadd(cmul(conjf2(c0v), mm), cmul(Du, Dj0));
        float2 t1 = cadd(cmul(conjf2(c1v), mm), cmul(Du, Dj1));
        float2 FX0 = cmul(fx, t0);
        float2 FX1 = cmul(fx, t1);
        sm_buf0[rs * 288 + PHI(t)] = make_float2(FX0.x * scale, FX0.y * scale);
        sm_buf0[rs * 288 + PHI(t + 128)] = make_float2(FX1.x * scale, FX1.y * scale);
    }
    __syncthreads();  // BARRIER 2: stage reads done before FFT st0 writes buf1

    // radix-4 Stockham IFFT (sigma=+1), wave-local: no barriers.
    // st0: buf0->buf1, st1: buf1->buf0, st2: buf0->buf1, st3 (jm=0, w=1):
    // in-place in buf1.
    {
        float2* Bc = sm_buf0;
        float2* Bn = sm_buf1;
        int m = 1;
#pragma unroll
        for (int st = 0; st < 3; ++st) {
            const int k = q & (m - 1);
            const int jm = q - k;
            const float2 w1 = tw[jm];
            const float2 w2 = tw[2 * jm];
            const float2 w3 = tw[3 * jm];
            float2 a0 = Bc[rs * 288 + PHI(q)];
            float2 a1 = Bc[rs * 288 + PHI(q + 64)];
            float2 a2 = Bc[rs * 288 + PHI(q + 128)];
            float2 a3 = Bc[rs * 288 + PHI(q + 192)];
            float2 s02 = cadd(a0, a2), d02 = csub(a0, a2);
            float2 s13 = cadd(a1, a3), d13 = csub(a1, a3);
            float2 b0 = cadd(s02, s13), b2v = csub(s02, s13);
            float2 b1 = make_float2(d02.x - d13.y, d02.y + d13.x);   // d02+i*d13
            float2 b3 = make_float2(d02.x + d13.y, d02.y - d13.x);   // d02-i*d13
            const int o = 4 * jm + k;
            Bn[rs * 288 + PHI(o)] = b0;
            Bn[rs * 288 + PHI(o + m)] = cmul(w1, b1);
            Bn[rs * 288 + PHI(o + 2 * m)] = cmul(w2, b2v);
            Bn[rs * 288 + PHI(o + 3 * m)] = cmul(w3, b3);
            float2* tp = Bc; Bc = Bn; Bn = tp;
            m <<= 2;
        }
        // st3: m=64, k=q, jm=0, w1=w2=w3=1; in-place (per-lane disjoint).
        {
            float2 a0 = Bc[rs * 288 + PHI(q)];
            float2 a1 = Bc[rs * 288 + PHI(q + 64)];
            float2 a2 = Bc[rs * 288 + PHI(q + 128)];
            float2 a3 = Bc[rs * 288 + PHI(q + 192)];
            float2 s02 = cadd(a0, a2), d02 = csub(a0, a2);
            float2 s13 = cadd(a1, a3), d13 = csub(a1, a3);
            Bc[rs * 288 + PHI(q)] = cadd(s02, s13);
            Bc[rs * 288 + PHI(q + 64)] = make_float2(d02.x - d13.y, d02.y + d13.x);
            Bc[rs * 288 + PHI(q + 128)] = csub(s02, s13);
            Bc[rs * 288 + PHI(q + 192)] = make_float2(d02.x + d13.y, d02.y - d13.x);
        }
    }
    __syncthreads();  // BARRIER 3: cross-wave fold reads rs^1 (data in buf1)

    // Hermitian fold: Zf[u0] = (Z[u0]+conj(Z[128-u0])) + i*w.(Z[u0]-conj(Z[128-u0]))
    const int u0 = u;
    bool dowrite = ((rs & 1) == 0) ? true : (p > 0 && p < 64);
    if (pb == pa && rs >= 2) dowrite = false;  // last-block dedup
    if (dowrite) {
        const float2 w = tw[u0];
        float2* zb = Zf + (size_t)img * 32768 + (size_t)u0 * 256;
#pragma unroll
        for (int hh = 0; hh < 4; ++hh) {
            const int jj = q + 64 * hh;
            float2 su = sm_buf1[rs * 288 + PHI(jj)];
            float2 s2 = sm_buf1[(rs ^ 1) * 288 + PHI(jj)];
            float2 e = make_float2(su.x + s2.x, su.y - s2.y);   // su + conj(s2)
            float2 o_ = make_float2(su.x - s2.x, su.y + s2.y);  // su - conj(s2)
            float2 wo = cmul(w, o_);
            zb[jj] = make_float2(e.x - wo.y, e.y + wo.x);       // e + i*wo
        }
    }
}

// K7: pure C2R column IFFT (wave-local radix-4), 16 cols/block.
__global__ __launch_bounds__(256) void k7_c2r(const float2* __restrict__ Zf,
                                              float* __restrict__ out) {
    __shared__ float2 buf[2][16][130];
    __shared__ float2 tw[96];  // e^{+i pi k/64}
    const int tid = threadIdx.x;
    const int img = blockIdx.x >> 4;
    const int c0 = (blockIdx.x & 15) * 16;
    for (int i = tid; i < 96; i += 256) {
        float s, c;
        __sincosf((float)M_PI * (float)i / 64.f, &s, &c);
        tw[i] = make_float2(c, s);
    }
    const float2* zb = Zf + (size_t)img * 32768 + c0;
    for (int it = 0; it < 8; ++it) {
        int idx = it * 256 + tid;
        int rr = idx >> 4, cc = idx & 15;
        buf[0][cc][rr] = zb[rr * 256 + cc];
    }
    __syncthreads();
    int cur = fft4_cols_wavelocal<1, 16>(buf, tw);
    __syncthreads();
    float* ob = out + (size_t)img * 65536 + c0;
    for (int it = 0; it < 8; ++it) {
        int idx = it * 256 + tid;
        int n = idx >> 4, c = idx & 15;
        float2 y = buf[cur][c][n];
        ob[(2 * n) * 256 + c] = y.x;
        ob[(2 * n + 1) * 256 + c] = y.y;
    }
}

extern "C" void kernel_launch(void* const* d_in, const int* in_sizes, int n_in,
                              void* d_out, int out_size, void* d_ws, size_t ws_size,
                              hipStream_t stream) {
    const float* x = (const float*)d_in[0];      // (4,64,128,128)
    const float* k = (const float*)d_in[1];      // (4,64,25,25)
    const float* alpha = (const float*)d_in[2];  // (1,64,1,1)
    float* out = (float*)d_out;                  // (4,64,256,256)

    float2* Fx = (float2*)d_ws;           // 256*16384   = 32 MB (cols 0..64 live)
    float2* Zf = Fx + 256 * 16384;        // 256*128*256 = 64 MB (folded)
    float2* FBtmp = Zf + 256 * 32768;     // 256*25*256  = 13.1 MB

    hipLaunchKernelGGL(k1_fft_rows_x, dim3(4096), dim3(256), 0, stream, x, Fx);
    hipLaunchKernelGGL(k2_fft_cols_x, dim3(256 * 5), dim3(256), 0, stream, Fx);
    hipLaunchKernelGGL(k3_fft_rows_k, dim3(6400), dim3(128), 0, stream, k, FBtmp);
    hipLaunchKernelGGL(k6_fused, dim3(256 * 33), dim3(256), 0, stream, FBtmp, Fx, alpha, Zf);
    hipLaunchKernelGGL(k7_c2r, dim3(4096), dim3(256), 0, stream, Zf, out);
}

// Round 7
// 181.328 us; speedup vs baseline: 2.4735x; 2.4735x over previous
//
#include <hip/hip_runtime.h>
#include <math.h>

// Closed-form pipeline with Hermitian (real-output) symmetry:
//   Fx  = fft2_128(x), stored cols 0..64 only (x real -> 2D-Hermitian)
//   FBtmp = row FFTs (N=256) of 25 psf rows (k3)
//   k6 fused: per-block on-the-fly column DFT of FBtmp -> 4 FBh rows;
//             M=(1-S1)/(S2+b); FX rows; radix-4 row IFFT (wave-local,
//             barrier-free); Hermitian fold; write Zf[0..127]
//   k7: pure 128-pt C2R column IFFT of Zf (wave-local radix-4)
// R7: j-invariant twiddles -> cooperative LDS twiddle tables everywhere.
// R8: single HB-table serves all Stockham stages; fold moved into k6.
// R9: radix-4 Stockham; k6 wave-owns-row -> no barriers in FFT loop.
// R10: Fx 2D-Hermitian halving; k2/k7 wave-local columns ([col][130] pad).
// R11: FBh round-trip eliminated; k6 computes 4 rows from FBtmp via 25-tap
//   dots; mirror rows from conj/(-1)^p recombination (same products).
// R12: LDS overlays: Tt in buf0, stage in buf1 -> 19.5 KB, 8 blocks/CU cap;
//   FFT stage 3 (jm=0, w=1) peeled twiddle-free in-place.
// R13: __launch_bounds__(256,8) forced VGPR 64->32 -> S[25] spilled to
//   scratch (FETCH 541MB, WRITE 1.02GB, k6 319us). Min-waves hint must stay
//   BELOW the live-register floor: use (256,4) (VGPR cap 128, natural 64).

static __device__ __forceinline__ float2 cmul(float2 a, float2 b) {
    return make_float2(a.x * b.x - a.y * b.y, a.x * b.y + a.y * b.x);
}
static __device__ __forceinline__ float2 cadd(float2 a, float2 b) {
    return make_float2(a.x + b.x, a.y + b.y);
}
static __device__ __forceinline__ float2 csub(float2 a, float2 b) {
    return make_float2(a.x - b.x, a.y - b.y);
}
static __device__ __forceinline__ float2 conjf2(float2 a) {
    return make_float2(a.x, -a.y);
}
static __device__ __forceinline__ int PHI(int i) { return i + (i >> 3); }

// Fill tw[i] = (cos(SIGN*pi*i/HB), sin(SIGN*pi*i/HB)) for i in [0,HB).
template <int HB, int SIGN, int THREADS>
static __device__ __forceinline__ void fill_tw(float2* tw) {
    for (int i = threadIdx.x; i < HB; i += THREADS) {
        float s, c;
        __sincosf((float)SIGN * (float)M_PI * (float)i / (float)HB, &s, &c);
        tw[i] = make_float2(c, s);
    }
}

// ---------------- radix-2 Stockham rows (k1/k3) ----------------
template <int N, int R, int SIGN>
static __device__ __forceinline__ int fft_lds_rows(float2 (&buf)[2][R][N],
                                                   const float2* __restrict__ tw) {
    constexpr int HB = N / 2;
    const int tid = threadIdx.x;
    const int row = tid / HB;
    const int bt = tid % HB;
    int cur = 0, m = 1;
    for (int l = HB; l >= 1; l >>= 1) {
        __syncthreads();
        const int k = bt & (m - 1);
        const float2 w = tw[bt - k];
        float2 a = buf[cur][row][bt];
        float2 b = buf[cur][row][bt + HB];
        float2 d = make_float2(a.x - b.x, a.y - b.y);
        float2 wd = make_float2(w.x * d.x - w.y * d.y, w.x * d.y + w.y * d.x);
        const int o = 2 * bt - k;
        buf[cur ^ 1][row][o] = make_float2(a.x + b.x, a.y + b.y);
        buf[cur ^ 1][row][o + m] = wd;
        cur ^= 1;
        m <<= 1;
    }
    __syncthreads();
    return cur;
}

// ------------- wave-local mixed radix-4/2 128-pt column FFT -------------
template <int SIGN, int NCOL>
static __device__ __forceinline__ int fft4_cols_wavelocal(float2 (&buf)[2][NCOL][130],
                                                          const float2* __restrict__ tw) {
    const int lane = threadIdx.x & 63;
    const int wv = threadIdx.x >> 6;
    const int col = wv * 4 + (lane >> 4);
    const int r = lane & 15;
    int cur = 0, m = 1;
#pragma unroll
    for (int st = 0; st < 3; ++st) {
#pragma unroll
        for (int b = 0; b < 2; ++b) {
            const int bq = r + 16 * b;
            const int k = bq & (m - 1);
            const int jm = bq - k;
            const float2 w1 = tw[jm];
            const float2 w2 = tw[2 * jm];
            const float2 w3 = tw[3 * jm];
            float2 a0 = buf[cur][col][bq];
            float2 a1 = buf[cur][col][bq + 32];
            float2 a2 = buf[cur][col][bq + 64];
            float2 a3 = buf[cur][col][bq + 96];
            float2 s02 = cadd(a0, a2), d02 = csub(a0, a2);
            float2 s13 = cadd(a1, a3), d13 = csub(a1, a3);
            float2 b0 = cadd(s02, s13), b2 = csub(s02, s13);
            float2 b1 = make_float2(d02.x - (float)SIGN * d13.y,
                                    d02.y + (float)SIGN * d13.x);
            float2 b3 = make_float2(d02.x + (float)SIGN * d13.y,
                                    d02.y - (float)SIGN * d13.x);
            const int o = 4 * jm + k;
            buf[cur ^ 1][col][o] = b0;
            buf[cur ^ 1][col][o + m] = cmul(w1, b1);
            buf[cur ^ 1][col][o + 2 * m] = cmul(w2, b2);
            buf[cur ^ 1][col][o + 3 * m] = cmul(w3, b3);
        }
        cur ^= 1;
        m <<= 2;
    }
#pragma unroll
    for (int b = 0; b < 4; ++b) {  // radix-2 tail, m=64, j=0
        const int bt = r + 16 * b;
        float2 a = buf[cur][col][bt];
        float2 bb = buf[cur][col][bt + 64];
        buf[cur ^ 1][col][bt] = cadd(a, bb);
        buf[cur ^ 1][col][bt + 64] = csub(a, bb);
    }
    return cur ^ 1;
}

// K1: row FFT of x (N=128) with pack-2; write only cols 0..64 (Hermitian).
__global__ __launch_bounds__(256) void k1_fft_rows_x(const float* __restrict__ x,
                                                     float2* __restrict__ Fx) {
    __shared__ float2 buf[2][4][128];
    __shared__ float2 tw64m[64];
    const int tid = threadIdx.x;
    const int row = tid >> 6;   // pair slot 0..3
    const int t = tid & 63;
    fill_tw<64, -1, 256>(tw64m);
    const int gpair = blockIdx.x * 4 + row;  // img*64 + pr
    const float* r0 = x + (size_t)gpair * 256;        // row 2*pr (128 floats)
    const float* r1 = r0 + 128;                       // row 2*pr+1
    const float2 a0 = ((const float2*)r0)[t];
    const float2 a1 = ((const float2*)r1)[t];
    buf[0][row][2 * t].x = a0.x;
    buf[0][row][2 * t].y = a1.x;
    buf[0][row][2 * t + 1].x = a0.y;
    buf[0][row][2 * t + 1].y = a1.y;
    int cur = fft_lds_rows<128, 4, -1>(buf, tw64m);
    float2* d0 = Fx + (size_t)gpair * 256;            // Fx row 2*pr
    float2* d1 = d0 + 128;
    for (int h = 0; h < 2; ++h) {
        int tt = t + h * 64;
        if (tt > 64) continue;  // Hermitian: cols 65..127 reconstructed in k6
        float2 Zt = buf[cur][row][tt];
        float2 Zm = buf[cur][row][(128 - tt) & 127];
        d0[tt] = make_float2(0.5f * (Zt.x + Zm.x), 0.5f * (Zt.y - Zm.y));
        float ax = Zt.x - Zm.x, ay = Zt.y + Zm.y;
        d1[tt] = make_float2(0.5f * ay, -0.5f * ax);
    }
}

// K2: column FFT of Fx, in place, cols 0..64 only -> 5 tiles of 16.
__global__ __launch_bounds__(256) void k2_fft_cols_x(float2* __restrict__ Fx) {
    __shared__ float2 buf[2][16][130];
    __shared__ float2 tw[96];
    const int tid = threadIdx.x;
    const int img = blockIdx.x / 5;
    const int c0 = (blockIdx.x % 5) * 16;
    for (int i = tid; i < 96; i += 256) {
        float s, c;
        __sincosf(-(float)M_PI * (float)i / 64.f, &s, &c);
        tw[i] = make_float2(c, s);
    }
    float2* base = Fx + (size_t)img * 16384 + c0;
    for (int it = 0; it < 8; ++it) {
        int idx = it * 256 + tid;
        int rr = idx >> 4, cc = idx & 15;
        buf[0][cc][rr] = base[rr * 128 + cc];
    }
    __syncthreads();
    int cur = fft4_cols_wavelocal<-1, 16>(buf, tw);
    __syncthreads();
    for (int it = 0; it < 8; ++it) {
        int idx = it * 256 + tid;
        int rr = idx >> 4, cc = idx & 15;
        base[rr * 128 + cc] = buf[cur][cc][rr];
    }
}

// K3: row FFT of padded+rolled psf (N=256), compact output [img][25][256].
__global__ __launch_bounds__(128) void k3_fft_rows_k(const float* __restrict__ kin,
                                                     float2* __restrict__ FBtmp) {
    __shared__ float2 buf[2][1][256];
    __shared__ float2 tw128m[128];
    const int tid = threadIdx.x;  // 128
    const int img = blockIdx.x / 25;
    const int lr = blockIdx.x % 25;
    fill_tw<128, -1, 128>(tw128m);
    const float* krow = kin + img * 625 + lr * 25;
    for (int h = 0; h < 2; ++h) {
        int v = tid + h * 128;
        int pc = (v + 12) & 255;
        buf[0][0][v] = make_float2(pc < 25 ? krow[pc] : 0.f, 0.f);
    }
    int cur = fft_lds_rows<256, 1, -1>(buf, tw128m);
    float2* dst = FBtmp + (size_t)img * 6400 + lr * 256;
    dst[tid] = buf[cur][0][tid];
    dst[tid + 128] = buf[cur][0][tid + 128];
}

// K6: fused column-DFT + M + FX build + radix-4 row IFFT + Hermitian fold.
// Block = (img, p-pair {pa=2b, pb=2b+1}); wave rs owns one of 4 rows.
// LDS overlays (R12): Tt lives in buf0 (consumed before buf0's first write);
// stage lives in buf1 (consumed before FFT st0 writes buf1; extra barrier).
// R13: min-waves hint 4 (VGPR cap 128) -- 8 forced VGPR=32 and spilled S[25].
__global__ __launch_bounds__(256, 4) void k6_fused(const float2* __restrict__ FBtmp,
                                                   const float2* __restrict__ Fx,
                                                   const float* __restrict__ alpha,
                                                   float2* __restrict__ Zf) {
    __shared__ float2 sm_buf0[4 * 288];  // FFT ping buffer; first 50 = Tt
    __shared__ float2 sm_buf1[4 * 288];  // FFT pong buffer; first 1024 = stage
    __shared__ float2 tw[192];           // e^{+i pi k/128}, k<192
    float2* Tt = sm_buf0;                // [2][25] flat: which*25+p
    float2* stageF = sm_buf1;            // [4][256] flat: s*256+i
    const int tid = threadIdx.x;
    const int rs = tid >> 6;             // row slot = wave id
    const int q = tid & 63;
    const int img = blockIdx.x / 33;
    const int bq = blockIdx.x % 33;
    const int pa = 2 * bq;
    const int pb = (pa + 1 < 65) ? (pa + 1) : 64;   // last block: pb==pa==64

    // Issue S loads early (coalesced over j=tid; FBtmp slab is L2-resident).
    const float2* src = FBtmp + (size_t)img * 6400 + tid;
    float2 S[25];
#pragma unroll
    for (int p = 0; p < 25; ++p) S[p] = src[p * 256];

    for (int i = tid; i < 192; i += 256) {
        float s, c;
        __sincosf((float)M_PI * (float)i / 128.f, &s, &c);
        tw[i] = make_float2(c, s);
    }
    {  // DFT twiddles: T_u[p] = W_256^{u(p+244)}, W = e^{-2pi i/256}
        const float k2pi = -2.f * (float)M_PI / 256.f;
        for (int i = tid; i < 50; i += 256) {
            const int which = i / 25, p = i - which * 25;
            const int u = which ? pb : pa;
            float s, c;
            __sincosf(k2pi * (float)((u * (p + 244)) & 255), &s, &c);
            Tt[which * 25 + p] = make_float2(c, s);
        }
    }
    __syncthreads();  // BARRIER 0: Tt visible

    // On-the-fly column DFT: 4 rows. Mirror row 128-u via
    //   FBh[128-u][j] = sum_p (-1)^p S[p] conj(T_u[p])  (same 4 products).
    {
        float2 aA = make_float2(0.f, 0.f), bA = make_float2(0.f, 0.f);
        float2 aB = make_float2(0.f, 0.f), bB = make_float2(0.f, 0.f);
#pragma unroll
        for (int p = 0; p < 25; ++p) {
            const float2 s = S[p];
            const float2 ta = Tt[p];
            const float axx = ta.x * s.x, ayy = ta.y * s.y;
            const float axy = ta.x * s.y, ayx = ta.y * s.x;
            aA.x += axx - ayy;
            aA.y += axy + ayx;
            if (p & 1) {
                bA.x -= axx + ayy;
                bA.y -= axy - ayx;
            } else {
                bA.x += axx + ayy;
                bA.y += axy - ayx;
            }
            const float2 tb = Tt[25 + p];
            const float bxx = tb.x * s.x, byy = tb.y * s.y;
            const float bxy = tb.x * s.y, byx = tb.y * s.x;
            aB.x += bxx - byy;
            aB.y += bxy + byx;
            if (p & 1) {
                bB.x -= bxx + byy;
                bB.y -= bxy - byx;
            } else {
                bB.x += bxx + byy;
                bB.y += bxy - byx;
            }
        }
        stageF[tid] = aA;          // FBh[pa]
        stageF[256 + tid] = bA;    // FBh[128-pa]
        stageF[512 + tid] = aB;    // FBh[pb]
        stageF[768 + tid] = bB;    // FBh[128-pb]
    }
    __syncthreads();  // BARRIER 1: stage[] visible (Tt dead; buf0 free)

    const int p = (rs < 2) ? pa : pb;
    const int sb = rs & 2;
    const int u = ((rs & 1) == 0) ? p : (128 - p);   // 0..128
    const int um = u & 127;
    const int msel = (um == p) ? 0 : 1;
    const int mi = sb | msel;
    const int oi = sb | (1 - msel);

    const float ci = tw[um].x, si = -tw[um].y;
    const float b = 1.f / (1.f + __expf(9.f - alpha[img & 63])) + 1e-3f;
    const float scale = 1.f / 65536.f;
    const float2 Di0 = make_float2(1.f + ci, si);
    const float2 Di1 = make_float2(1.f - ci, -si);
    const float2 Du = (u < 128) ? Di0 : Di1;
#pragma unroll
    for (int h = 0; h < 2; ++h) {
        const int t = q + 64 * h;        // 0..127
        float2 f00 = stageF[mi * 256 + t];
        float2 f01 = stageF[mi * 256 + t + 128];
        float2 f10, f11;
        if (um == 0) {  // rows {0,128}: row 128 direct
            f10 = stageF[oi * 256 + t];
            f11 = stageF[oi * 256 + t + 128];
        } else {
            f10 = conjf2(stageF[oi * 256 + ((256 - t) & 255)]);
            f11 = conjf2(stageF[oi * 256 + 128 - t]);
        }
        // Fx stored cols 0..64 only; mirror t>64: conj(Fx[(128-um)%128][128-t])
        const bool mir = (t > 64);
        const int rr = mir ? ((128 - um) & 127) : um;
        const int cc = mir ? (128 - t) : t;
        float2 fx = Fx[(size_t)img * 16384 + rr * 128 + cc];
        if (mir) fx.y = -fx.y;
        const float cj = tw[t].x, sj = -tw[t].y;
        float2 Dj0 = make_float2(1.f + cj, sj);
        float2 Dj1 = make_float2(1.f - cj, -sj);
        // S1 = (f00*Dj0 + f01*Dj1)*Di0 + (f10*Dj0 + f11*Dj1)*Di1  (6 cmuls)
        float2 A = cadd(cmul(f00, Dj0), cmul(f01, Dj1));
        float2 Bt = cadd(cmul(f10, Dj0), cmul(f11, Dj1));
        float2 S1 = cadd(cmul(A, Di0), cmul(Bt, Di1));
        S1.x *= 0.25f;
        S1.y *= 0.25f;
        float S2 = 0.25f * (f00.x * f00.x + f00.y * f00.y + f01.x * f01.x + f01.y * f01.y +
                            f10.x * f10.x + f10.y * f10.y + f11.x * f11.x + f11.y * f11.y);
        float inv = 1.f / (S2 + b);
        float2 mm = make_float2((1.f - S1.x) * inv, (-S1.y) * inv);
        float2 c0v = (u < 128) ? f00 : f10;
        float2 c1v = (u < 128) ? f01 : f11;
        float2 t0 = cadd(cmul(conjf2(c0v), mm), cmul(Du, Dj0));
        float2 t1 = cadd(cmul(conjf2(c1v), mm), cmul(Du, Dj1));
        float2 FX0 = cmul(fx, t0);
        float2 FX1 = cmul(fx, t1);
        sm_buf0[rs * 288 + PHI(t)] = make_float2(FX0.x * scale, FX0.y * scale);
        sm_buf0[rs * 288 + PHI(t + 128)] = make_float2(FX1.x * scale, FX1.y * scale);
    }
    __syncthreads();  // BARRIER 2: stage reads done before FFT st0 writes buf1

    // radix-4 Stockham IFFT (sigma=+1), wave-local: no barriers.
    // st0: buf0->buf1, st1: buf1->buf0, st2: buf0->buf1, st3 (jm=0, w=1):
    // in-place in buf1.
    {
        float2* Bc = sm_buf0;
        float2* Bn = sm_buf1;
        int m = 1;
#pragma unroll
        for (int st = 0; st < 3; ++st) {
            const int k = q & (m - 1);
            const int jm = q - k;
            const float2 w1 = tw[jm];
            const float2 w2 = tw[2 * jm];
            const float2 w3 = tw[3 * jm];
            float2 a0 = Bc[rs * 288 + PHI(q)];
            float2 a1 = Bc[rs * 288 + PHI(q + 64)];
            float2 a2 = Bc[rs * 288 + PHI(q + 128)];
            float2 a3 = Bc[rs * 288 + PHI(q + 192)];
            float2 s02 = cadd(a0, a2), d02 = csub(a0, a2);
            float2 s13 = cadd(a1, a3), d13 = csub(a1, a3);
            float2 b0 = cadd(s02, s13), b2v = csub(s02, s13);
            float2 b1 = make_float2(d02.x - d13.y, d02.y + d13.x);   // d02+i*d13
            float2 b3 = make_float2(d02.x + d13.y, d02.y - d13.x);   // d02-i*d13
            const int o = 4 * jm + k;
            Bn[rs * 288 + PHI(o)] = b0;
            Bn[rs * 288 + PHI(o + m)] = cmul(w1, b1);
            Bn[rs * 288 + PHI(o + 2 * m)] = cmul(w2, b2v);
            Bn[rs * 288 + PHI(o + 3 * m)] = cmul(w3, b3);
            float2* tp = Bc; Bc = Bn; Bn = tp;
            m <<= 2;
        }
        // st3: m=64, k=q, jm=0, w1=w2=w3=1; in-place (per-lane disjoint).
        {
            float2 a0 = Bc[rs * 288 + PHI(q)];
            float2 a1 = Bc[rs * 288 + PHI(q + 64)];
            float2 a2 = Bc[rs * 288 + PHI(q + 128)];
            float2 a3 = Bc[rs * 288 + PHI(q + 192)];
            float2 s02 = cadd(a0, a2), d02 = csub(a0, a2);
            float2 s13 = cadd(a1, a3), d13 = csub(a1, a3);
            Bc[rs * 288 + PHI(q)] = cadd(s02, s13);
            Bc[rs * 288 + PHI(q + 64)] = make_float2(d02.x - d13.y, d02.y + d13.x);
            Bc[rs * 288 + PHI(q + 128)] = csub(s02, s13);
            Bc[rs * 288 + PHI(q + 192)] = make_float2(d02.x + d13.y, d02.y - d13.x);
        }
    }
    __syncthreads();  // BARRIER 3: cross-wave fold reads rs^1 (data in buf1)

    // Hermitian fold: Zf[u0] = (Z[u0]+conj(Z[128-u0])) + i*w.(Z[u0]-conj(Z[128-u0]))
    const int u0 = u;
    bool dowrite = ((rs & 1) == 0) ? true : (p > 0 && p < 64);
    if (pb == pa && rs >= 2) dowrite = false;  // last-block dedup
    if (dowrite) {
        const float2 w = tw[u0];
        float2* zb = Zf + (size_t)img * 32768 + (size_t)u0 * 256;
#pragma unroll
        for (int hh = 0; hh < 4; ++hh) {
            const int jj = q + 64 * hh;
            float2 su = sm_buf1[rs * 288 + PHI(jj)];
            float2 s2 = sm_buf1[(rs ^ 1) * 288 + PHI(jj)];
            float2 e = make_float2(su.x + s2.x, su.y - s2.y);   // su + conj(s2)
            float2 o_ = make_float2(su.x - s2.x, su.y + s2.y);  // su - conj(s2)
            float2 wo = cmul(w, o_);
            zb[jj] = make_float2(e.x - wo.y, e.y + wo.x);       // e + i*wo
        }
    }
}

// K7: pure C2R column IFFT (wave-local radix-4), 16 cols/block.
__global__ __launch_bounds__(256) void k7_c2r(const float2* __restrict__ Zf,
                                              float* __restrict__ out) {
    __shared__ float2 buf[2][16][130];
    __shared__ float2 tw[96];  // e^{+i pi k/64}
    const int tid = threadIdx.x;
    const int img = blockIdx.x >> 4;
    const int c0 = (blockIdx.x & 15) * 16;
    for (int i = tid; i < 96; i += 256) {
        float s, c;
        __sincosf((float)M_PI * (float)i / 64.f, &s, &c);
        tw[i] = make_float2(c, s);
    }
    const float2* zb = Zf + (size_t)img * 32768 + c0;
    for (int it = 0; it < 8; ++it) {
        int idx = it * 256 + tid;
        int rr = idx >> 4, cc = idx & 15;
        buf[0][cc][rr] = zb[rr * 256 + cc];
    }
    __syncthreads();
    int cur = fft4_cols_wavelocal<1, 16>(buf, tw);
    __syncthreads();
    float* ob = out + (size_t)img * 65536 + c0;
    for (int it = 0; it < 8; ++it) {
        int idx = it * 256 + tid;
        int n = idx >> 4, c = idx & 15;
        float2 y = buf[cur][c][n];
        ob[(2 * n) * 256 + c] = y.x;
        ob[(2 * n + 1) * 256 + c] = y.y;
    }
}

extern "C" void kernel_launch(void* const* d_in, const int* in_sizes, int n_in,
                              void* d_out, int out_size, void* d_ws, size_t ws_size,
                              hipStream_t stream) {
    const float* x = (const float*)d_in[0];      // (4,64,128,128)
    const float* k = (const float*)d_in[1];      // (4,64,25,25)
    const float* alpha = (const float*)d_in[2];  // (1,64,1,1)
    float* out = (float*)d_out;                  // (4,64,256,256)

    float2* Fx = (float2*)d_ws;           // 256*16384   = 32 MB (cols 0..64 live)
    float2* Zf = Fx + 256 * 16384;        // 256*128*256 = 64 MB (folded)
    float2* FBtmp = Zf + 256 * 32768;     // 256*25*256  = 13.1 MB

    hipLaunchKernelGGL(k1_fft_rows_x, dim3(4096), dim3(256), 0, stream, x, Fx);
    hipLaunchKernelGGL(k2_fft_cols_x, dim3(256 * 5), dim3(256), 0, stream, Fx);
    hipLaunchKernelGGL(k3_fft_rows_k, dim3(6400), dim3(128), 0, stream, k, FBtmp);
    hipLaunchKernelGGL(k6_fused, dim3(256 * 33), dim3(256), 0, stream, FBtmp, Fx, alpha, Zf);
    hipLaunchKernelGGL(k7_c2r, dim3(4096), dim3(256), 0, stream, Zf, out);
}

// Round 8
// 178.847 us; speedup vs baseline: 2.5078x; 1.0139x over previous
//
#include <hip/hip_runtime.h>
#include <math.h>

// Closed-form pipeline with Hermitian (real-output) symmetry:
//   k13: blocks [0,4096) row-FFT of x (pack-2, cols 0..64); blocks beyond:
//        row FFTs (N=256) of psf rows, 2 rows/block -> FBtmp
//   k2:  column FFT of Fx (wave-local radix-4), cols 0..64
//   k6 fused: on-the-fly column DFT of FBtmp -> 4 FBh rows; M=(1-S1)/(S2+b);
//             FX; radix-4 row IFFT with stage1+stage4 IN REGISTERS;
//             Hermitian fold; write Zf[0..127]
//   k7:  pure 128-pt C2R column IFFT of Zf (wave-local radix-4)
// R7: j-invariant twiddles -> cooperative LDS twiddle tables everywhere.
// R9: radix-4 Stockham; k6 wave-owns-row -> no barriers in FFT loop.
// R10: Fx 2D-Hermitian halving; k2/k7 wave-local columns ([col][130] pad).
// R11: FBh never materialized; k6 does 25-tap dots; mirror rows via (-1)^p.
// R12: LDS overlays (Tt in buf0, stage in buf1) -> 19.5 KB.
// R13: launch_bounds min-waves must stay BELOW live-reg floor: (256,4).
// R14: k6 is ISSUE-bound (VALUBusy 80%, occ flat vs R12) -> instruction diet:
//   (a) FFT stage1 in regs (FX set {q,q+64,q+128,q+192} already in regs;
//       the LDS write+readback was pure waste); consecutive outputs as b128;
//   (b) stage4 (jm=0) outputs stay in regs, feed fold; only partner copy
//       goes through LDS (-4 reads);
//   (c) PHI16 pad i+((i>>4)<<1): 16B-aligned b128 + ~2-way scatter writes;
//   (d) k1+k3 merged (5 launches -> 4, ~10us gap saved).

static __device__ __forceinline__ float2 cmul(float2 a, float2 b) {
    return make_float2(a.x * b.x - a.y * b.y, a.x * b.y + a.y * b.x);
}
static __device__ __forceinline__ float2 cadd(float2 a, float2 b) {
    return make_float2(a.x + b.x, a.y + b.y);
}
static __device__ __forceinline__ float2 csub(float2 a, float2 b) {
    return make_float2(a.x - b.x, a.y - b.y);
}
static __device__ __forceinline__ float2 conjf2(float2 a) {
    return make_float2(a.x, -a.y);
}
static __device__ __forceinline__ int PHI16(int i) { return i + ((i >> 4) << 1); }

// Fill tw[i] = (cos(SIGN*pi*i/HB), sin(SIGN*pi*i/HB)) for i in [0,HB).
template <int HB, int SIGN, int THREADS>
static __device__ __forceinline__ void fill_tw(float2* tw) {
    for (int i = threadIdx.x; i < HB; i += THREADS) {
        float s, c;
        __sincosf((float)SIGN * (float)M_PI * (float)i / (float)HB, &s, &c);
        tw[i] = make_float2(c, s);
    }
}

// ---------------- radix-2 Stockham rows (k13) ----------------
template <int N, int R, int SIGN>
static __device__ __forceinline__ int fft_lds_rows(float2 (&buf)[2][R][N],
                                                   const float2* __restrict__ tw) {
    constexpr int HB = N / 2;
    const int tid = threadIdx.x;
    const int row = tid / HB;
    const int bt = tid % HB;
    int cur = 0, m = 1;
    for (int l = HB; l >= 1; l >>= 1) {
        __syncthreads();
        const int k = bt & (m - 1);
        const float2 w = tw[bt - k];
        float2 a = buf[cur][row][bt];
        float2 b = buf[cur][row][bt + HB];
        float2 d = make_float2(a.x - b.x, a.y - b.y);
        float2 wd = make_float2(w.x * d.x - w.y * d.y, w.x * d.y + w.y * d.x);
        const int o = 2 * bt - k;
        buf[cur ^ 1][row][o] = make_float2(a.x + b.x, a.y + b.y);
        buf[cur ^ 1][row][o + m] = wd;
        cur ^= 1;
        m <<= 1;
    }
    __syncthreads();
    return cur;
}

// ------------- wave-local mixed radix-4/2 128-pt column FFT -------------
template <int SIGN, int NCOL>
static __device__ __forceinline__ int fft4_cols_wavelocal(float2 (&buf)[2][NCOL][130],
                                                          const float2* __restrict__ tw) {
    const int lane = threadIdx.x & 63;
    const int wv = threadIdx.x >> 6;
    const int col = wv * 4 + (lane >> 4);
    const int r = lane & 15;
    int cur = 0, m = 1;
#pragma unroll
    for (int st = 0; st < 3; ++st) {
#pragma unroll
        for (int b = 0; b < 2; ++b) {
            const int bq = r + 16 * b;
            const int k = bq & (m - 1);
            const int jm = bq - k;
            const float2 w1 = tw[jm];
            const float2 w2 = tw[2 * jm];
            const float2 w3 = tw[3 * jm];
            float2 a0 = buf[cur][col][bq];
            float2 a1 = buf[cur][col][bq + 32];
            float2 a2 = buf[cur][col][bq + 64];
            float2 a3 = buf[cur][col][bq + 96];
            float2 s02 = cadd(a0, a2), d02 = csub(a0, a2);
            float2 s13 = cadd(a1, a3), d13 = csub(a1, a3);
            float2 b0 = cadd(s02, s13), b2 = csub(s02, s13);
            float2 b1 = make_float2(d02.x - (float)SIGN * d13.y,
                                    d02.y + (float)SIGN * d13.x);
            float2 b3 = make_float2(d02.x + (float)SIGN * d13.y,
                                    d02.y - (float)SIGN * d13.x);
            const int o = 4 * jm + k;
            buf[cur ^ 1][col][o] = b0;
            buf[cur ^ 1][col][o + m] = cmul(w1, b1);
            buf[cur ^ 1][col][o + 2 * m] = cmul(w2, b2);
            buf[cur ^ 1][col][o + 3 * m] = cmul(w3, b3);
        }
        cur ^= 1;
        m <<= 2;
    }
#pragma unroll
    for (int b = 0; b < 4; ++b) {  // radix-2 tail, m=64, j=0
        const int bt = r + 16 * b;
        float2 a = buf[cur][col][bt];
        float2 bb = buf[cur][col][bt + 64];
        buf[cur ^ 1][col][bt] = cadd(a, bb);
        buf[cur ^ 1][col][bt + 64] = csub(a, bb);
    }
    return cur ^ 1;
}

// K13: merged k1 (x row FFT, pack-2, Hermitian cols 0..64) + k3 (psf row FFT).
// Blocks [0,4096): k1 work. Blocks [4096, 4096+3328): k3, 2 rows/block.
__global__ __launch_bounds__(256) void k13(const float* __restrict__ x,
                                           const float* __restrict__ kin,
                                           float2* __restrict__ Fx,
                                           float2* __restrict__ FBtmp) {
    __shared__ __align__(16) float2 pool[1152];  // max(k1: 1024+64, k3: 1024+128)
    const int tid = threadIdx.x;
    if (blockIdx.x < 4096) {
        using Buf1 = float2[2][4][128];
        Buf1& buf = *reinterpret_cast<Buf1*>(pool);
        float2* tw64m = pool + 1024;
        const int row = tid >> 6;   // pair slot 0..3
        const int t = tid & 63;
        fill_tw<64, -1, 256>(tw64m);
        const int gpair = blockIdx.x * 4 + row;  // img*64 + pr
        const float* r0 = x + (size_t)gpair * 256;
        const float* r1 = r0 + 128;
        const float2 a0 = ((const float2*)r0)[t];
        const float2 a1 = ((const float2*)r1)[t];
        buf[0][row][2 * t].x = a0.x;
        buf[0][row][2 * t].y = a1.x;
        buf[0][row][2 * t + 1].x = a0.y;
        buf[0][row][2 * t + 1].y = a1.y;
        int cur = fft_lds_rows<128, 4, -1>(buf, tw64m);
        float2* d0 = Fx + (size_t)gpair * 256;
        float2* d1 = d0 + 128;
        for (int h = 0; h < 2; ++h) {
            int tt = t + h * 64;
            if (tt > 64) continue;  // Hermitian: cols 65..127 rebuilt in k6
            float2 Zt = buf[cur][row][tt];
            float2 Zm = buf[cur][row][(128 - tt) & 127];
            d0[tt] = make_float2(0.5f * (Zt.x + Zm.x), 0.5f * (Zt.y - Zm.y));
            float ax = Zt.x - Zm.x, ay = Zt.y + Zm.y;
            d1[tt] = make_float2(0.5f * ay, -0.5f * ax);
        }
    } else {
        using Buf3 = float2[2][2][256];
        Buf3& buf = *reinterpret_cast<Buf3*>(pool);
        float2* tw128m = pool + 1024;
        const int b3 = blockIdx.x - 4096;
        const int img = b3 / 13;
        const int sub = b3 % 13;
        const int row = tid >> 7;           // 0..1
        const int t2 = tid & 127;
        int lr = sub * 2 + row;
        const bool live = (lr < 25);
        if (!live) lr = 24;                 // dead group computes garbage, no store
        fill_tw<128, -1, 256>(tw128m);
        const float* krow = kin + img * 625 + lr * 25;
        for (int h = 0; h < 2; ++h) {
            int v = t2 + h * 128;
            int pc = (v + 12) & 255;
            buf[0][row][v] = make_float2(pc < 25 ? krow[pc] : 0.f, 0.f);
        }
        int cur = fft_lds_rows<256, 2, -1>(buf, tw128m);
        if (live) {
            float2* dst = FBtmp + (size_t)img * 6400 + lr * 256;
            dst[t2] = buf[cur][row][t2];
            dst[t2 + 128] = buf[cur][row][t2 + 128];
        }
    }
}

// K2: column FFT of Fx, in place, cols 0..64 only -> 5 tiles of 16.
__global__ __launch_bounds__(256) void k2_fft_cols_x(float2* __restrict__ Fx) {
    __shared__ float2 buf[2][16][130];
    __shared__ float2 tw[96];
    const int tid = threadIdx.x;
    const int img = blockIdx.x / 5;
    const int c0 = (blockIdx.x % 5) * 16;
    for (int i = tid; i < 96; i += 256) {
        float s, c;
        __sincosf(-(float)M_PI * (float)i / 64.f, &s, &c);
        tw[i] = make_float2(c, s);
    }
    float2* base = Fx + (size_t)img * 16384 + c0;
    for (int it = 0; it < 8; ++it) {
        int idx = it * 256 + tid;
        int rr = idx >> 4, cc = idx & 15;
        buf[0][cc][rr] = base[rr * 128 + cc];
    }
    __syncthreads();
    int cur = fft4_cols_wavelocal<-1, 16>(buf, tw);
    __syncthreads();
    for (int it = 0; it < 8; ++it) {
        int idx = it * 256 + tid;
        int rr = idx >> 4, cc = idx & 15;
        base[rr * 128 + cc] = buf[cur][cc][rr];
    }
}

// K6: fused column-DFT + M + FX build + radix-4 row IFFT + Hermitian fold.
// Block = (img, p-pair {pa=2b, pb=2b+1}); wave rs owns one of 4 rows.
// R14: FFT stage1 (m=1) in regs -> b128 stores; stage4 (m=64, jm=0) in regs
// feeding the fold; stages m=4,16 via LDS (wave-local, in-order DS).
__global__ __launch_bounds__(256, 4) void k6_fused(const float2* __restrict__ FBtmp,
                                                   const float2* __restrict__ Fx,
                                                   const float* __restrict__ alpha,
                                                   float2* __restrict__ Zf) {
    __shared__ __align__(16) float2 sm_buf0[4 * 288];  // Tt overlay; FFT buf A
    __shared__ __align__(16) float2 sm_buf1[4 * 288];  // stage overlay; FFT buf B
    __shared__ float2 tw[192];                         // e^{+i pi k/128}, k<192
    float2* Tt = sm_buf0;                // [2][25] flat
    float2* stageF = sm_buf1;            // [4][256] flat
    const int tid = threadIdx.x;
    const int rs = tid >> 6;             // row slot = wave id
    const int q = tid & 63;
    const int img = blockIdx.x / 33;
    const int bq = blockIdx.x % 33;
    const int pa = 2 * bq;
    const int pb = (pa + 1 < 65) ? (pa + 1) : 64;   // last block: pb==pa==64

    const float2* src = FBtmp + (size_t)img * 6400 + tid;
    float2 S[25];
#pragma unroll
    for (int p = 0; p < 25; ++p) S[p] = src[p * 256];

    for (int i = tid; i < 192; i += 256) {
        float s, c;
        __sincosf((float)M_PI * (float)i / 128.f, &s, &c);
        tw[i] = make_float2(c, s);
    }
    {  // DFT twiddles: T_u[p] = W_256^{u(p+244)}
        const float k2pi = -2.f * (float)M_PI / 256.f;
        for (int i = tid; i < 50; i += 256) {
            const int which = i / 25, p = i - which * 25;
            const int u = which ? pb : pa;
            float s, c;
            __sincosf(k2pi * (float)((u * (p + 244)) & 255), &s, &c);
            Tt[which * 25 + p] = make_float2(c, s);
        }
    }
    __syncthreads();  // B0: Tt visible

    // On-the-fly column DFT: 4 rows; mirror rows via (-1)^p + conj.
    {
        float2 aA = make_float2(0.f, 0.f), bA = make_float2(0.f, 0.f);
        float2 aB = make_float2(0.f, 0.f), bB = make_float2(0.f, 0.f);
#pragma unroll
        for (int p = 0; p < 25; ++p) {
            const float2 s = S[p];
            const float2 ta = Tt[p];
            const float axx = ta.x * s.x, ayy = ta.y * s.y;
            const float axy = ta.x * s.y, ayx = ta.y * s.x;
            aA.x += axx - ayy;
            aA.y += axy + ayx;
            if (p & 1) {
                bA.x -= axx + ayy;
                bA.y -= axy - ayx;
            } else {
                bA.x += axx + ayy;
                bA.y += axy - ayx;
            }
            const float2 tb = Tt[25 + p];
            const float bxx = tb.x * s.x, byy = tb.y * s.y;
            const float bxy = tb.x * s.y, byx = tb.y * s.x;
            aB.x += bxx - byy;
            aB.y += bxy + byx;
            if (p & 1) {
                bB.x -= bxx + byy;
                bB.y -= bxy - byx;
            } else {
                bB.x += bxx + byy;
                bB.y += bxy - byx;
            }
        }
        stageF[tid] = aA;          // FBh[pa]
        stageF[256 + tid] = bA;    // FBh[128-pa]
        stageF[512 + tid] = aB;    // FBh[pb]
        stageF[768 + tid] = bB;    // FBh[128-pb]
    }
    __syncthreads();  // B1: stage visible (Tt dead; buf0 free)

    const int p = (rs < 2) ? pa : pb;
    const int sb = rs & 2;
    const int u = ((rs & 1) == 0) ? p : (128 - p);   // 0..128
    const int um = u & 127;
    const int msel = (um == p) ? 0 : 1;
    const int mi = sb | msel;
    const int oi = sb | (1 - msel);

    const float ci = tw[um].x, si = -tw[um].y;
    const float b = 1.f / (1.f + __expf(9.f - alpha[img & 63])) + 1e-3f;
    const float scale = 1.f / 65536.f;
    const float2 Di0 = make_float2(1.f + ci, si);
    const float2 Di1 = make_float2(1.f - ci, -si);
    const float2 Du = (u < 128) ? Di0 : Di1;
    float2 X0, X1, X2, X3;  // FX at cols q, q+64, q+128, q+192
#pragma unroll
    for (int h = 0; h < 2; ++h) {
        const int t = q + 64 * h;        // 0..127
        float2 f00 = stageF[mi * 256 + t];
        float2 f01 = stageF[mi * 256 + t + 128];
        float2 f10, f11;
        if (um == 0) {
            f10 = stageF[oi * 256 + t];
            f11 = stageF[oi * 256 + t + 128];
        } else {
            f10 = conjf2(stageF[oi * 256 + ((256 - t) & 255)]);
            f11 = conjf2(stageF[oi * 256 + 128 - t]);
        }
        // Fx stored cols 0..64; mirror t>64: conj(Fx[(128-um)%128][128-t])
        const bool mir = (t > 64);
        const int rr = mir ? ((128 - um) & 127) : um;
        const int cc = mir ? (128 - t) : t;
        float2 fx = Fx[(size_t)img * 16384 + rr * 128 + cc];
        if (mir) fx.y = -fx.y;
        const float cj = tw[t].x, sj = -tw[t].y;
        float2 Dj0 = make_float2(1.f + cj, sj);
        float2 Dj1 = make_float2(1.f - cj, -sj);
        float2 A = cadd(cmul(f00, Dj0), cmul(f01, Dj1));
        float2 Bt = cadd(cmul(f10, Dj0), cmul(f11, Dj1));
        float2 S1 = cadd(cmul(A, Di0), cmul(Bt, Di1));
        S1.x *= 0.25f;
        S1.y *= 0.25f;
        float S2 = 0.25f * (f00.x * f00.x + f00.y * f00.y + f01.x * f01.x + f01.y * f01.y +
                            f10.x * f10.x + f10.y * f10.y + f11.x * f11.x + f11.y * f11.y);
        float inv = 1.f / (S2 + b);
        float2 mm = make_float2((1.f - S1.x) * inv, (-S1.y) * inv);
        float2 c0v = (u < 128) ? f00 : f10;
        float2 c1v = (u < 128) ? f01 : f11;
        float2 t0 = cadd(cmul(conjf2(c0v), mm), cmul(Du, Dj0));
        float2 t1 = cadd(cmul(conjf2(c1v), mm), cmul(Du, Dj1));
        float2 FX0 = cmul(fx, t0);
        float2 FX1 = cmul(fx, t1);
        FX0.x *= scale; FX0.y *= scale;
        FX1.x *= scale; FX1.y *= scale;
        if (h == 0) { X0 = FX0; X2 = FX1; } else { X1 = FX0; X3 = FX1; }
    }

    // FFT stage m=1 in regs (jm=q, k=0): outputs at 4q..4q+3 -> 2x b128.
    {
        float2 s02 = cadd(X0, X2), d02 = csub(X0, X2);
        float2 s13 = cadd(X1, X3), d13 = csub(X1, X3);
        float2 b0 = cadd(s02, s13), b2v = csub(s02, s13);
        float2 b1 = make_float2(d02.x - d13.y, d02.y + d13.x);
        float2 b3 = make_float2(d02.x + d13.y, d02.y - d13.x);
        float2 c1 = cmul(tw[q], b1);
        float2 c2 = cmul(tw[2 * q], b2v);
        float2 c3 = cmul(tw[3 * q], b3);
        float4* dst4 = reinterpret_cast<float4*>(&sm_buf0[rs * 288 + PHI16(4 * q)]);
        dst4[0] = make_float4(b0.x, b0.y, c1.x, c1.y);
        dst4[1] = make_float4(c2.x, c2.y, c3.x, c3.y);
    }
    __syncthreads();  // B2: all stage (buf1) reads done before m=4 writes buf1

    // stage m=4: buf0 -> buf1 (wave-local)
    {
        const int k4 = q & 3, jm = q - k4;
        float2 a0 = sm_buf0[rs * 288 + PHI16(q)];
        float2 a1 = sm_buf0[rs * 288 + PHI16(q + 64)];
        float2 a2 = sm_buf0[rs * 288 + PHI16(q + 128)];
        float2 a3 = sm_buf0[rs * 288 + PHI16(q + 192)];
        float2 s02 = cadd(a0, a2), d02 = csub(a0, a2);
        float2 s13 = cadd(a1, a3), d13 = csub(a1, a3);
        float2 b0 = cadd(s02, s13), b2v = csub(s02, s13);
        float2 b1 = make_float2(d02.x - d13.y, d02.y + d13.x);
        float2 b3 = make_float2(d02.x + d13.y, d02.y - d13.x);
        const int o = 4 * jm + k4;
        sm_buf1[rs * 288 + PHI16(o)] = b0;
        sm_buf1[rs * 288 + PHI16(o + 4)] = cmul(tw[jm], b1);
        sm_buf1[rs * 288 + PHI16(o + 8)] = cmul(tw[2 * jm], b2v);
        sm_buf1[rs * 288 + PHI16(o + 12)] = cmul(tw[3 * jm], b3);
    }
    // stage m=16: buf1 -> buf0 (wave-local, in-order DS)
    {
        const int k16 = q & 15, jm = q - k16;
        float2 a0 = sm_buf1[rs * 288 + PHI16(q)];
        float2 a1 = sm_buf1[rs * 288 + PHI16(q + 64)];
        float2 a2 = sm_buf1[rs * 288 + PHI16(q + 128)];
        float2 a3 = sm_buf1[rs * 288 + PHI16(q + 192)];
        float2 s02 = cadd(a0, a2), d02 = csub(a0, a2);
        float2 s13 = cadd(a1, a3), d13 = csub(a1, a3);
        float2 b0 = cadd(s02, s13), b2v = csub(s02, s13);
        float2 b1 = make_float2(d02.x - d13.y, d02.y + d13.x);
        float2 b3 = make_float2(d02.x + d13.y, d02.y - d13.x);
        const int o = 4 * jm + k16;
        sm_buf0[rs * 288 + PHI16(o)] = b0;
        sm_buf0[rs * 288 + PHI16(o + 16)] = cmul(tw[jm], b1);
        sm_buf0[rs * 288 + PHI16(o + 32)] = cmul(tw[2 * jm], b2v);
        sm_buf0[rs * 288 + PHI16(o + 48)] = cmul(tw[3 * jm], b3);
    }
    // stage m=64 (jm=0, w=1) in regs: outputs at {q, q+64, q+128, q+192}.
    float2 Y0, Y1, Y2, Y3;
    {
        float2 a0 = sm_buf0[rs * 288 + PHI16(q)];
        float2 a1 = sm_buf0[rs * 288 + PHI16(q + 64)];
        float2 a2 = sm_buf0[rs * 288 + PHI16(q + 128)];
        float2 a3 = sm_buf0[rs * 288 + PHI16(q + 192)];
        float2 s02 = cadd(a0, a2), d02 = csub(a0, a2);
        float2 s13 = cadd(a1, a3), d13 = csub(a1, a3);
        Y0 = cadd(s02, s13);
        Y1 = make_float2(d02.x - d13.y, d02.y + d13.x);
        Y2 = csub(s02, s13);
        Y3 = make_float2(d02.x + d13.y, d02.y - d13.x);
    }
    // partner exchange for the fold (buf1 rs-region free after m=16 reads)
    sm_buf1[rs * 288 + PHI16(q)] = Y0;
    sm_buf1[rs * 288 + PHI16(q + 64)] = Y1;
    sm_buf1[rs * 288 + PHI16(q + 128)] = Y2;
    sm_buf1[rs * 288 + PHI16(q + 192)] = Y3;
    __syncthreads();  // B3: cross-wave fold reads rs^1

    // Hermitian fold: Zf[u0] = e + i*w.o, own values in regs, partner via LDS.
    const int u0 = u;
    bool dowrite = ((rs & 1) == 0) ? true : (p > 0 && p < 64);
    if (pb == pa && rs >= 2) dowrite = false;  // last-block dedup
    if (dowrite) {
        const float2 w = tw[u0];
        float2* zb = Zf + (size_t)img * 32768 + (size_t)u0 * 256;
        float2 own[4] = {Y0, Y1, Y2, Y3};
#pragma unroll
        for (int hh = 0; hh < 4; ++hh) {
            const int jj = q + 64 * hh;
            float2 su = own[hh];
            float2 s2 = sm_buf1[(rs ^ 1) * 288 + PHI16(jj)];
            float2 e = make_float2(su.x + s2.x, su.y - s2.y);   // su + conj(s2)
            float2 o_ = make_float2(su.x - s2.x, su.y + s2.y);  // su - conj(s2)
            float2 wo = cmul(w, o_);
            zb[jj] = make_float2(e.x - wo.y, e.y + wo.x);       // e + i*wo
        }
    }
}

// K7: pure C2R column IFFT (wave-local radix-4), 16 cols/block.
__global__ __launch_bounds__(256) void k7_c2r(const float2* __restrict__ Zf,
                                              float* __restrict__ out) {
    __shared__ float2 buf[2][16][130];
    __shared__ float2 tw[96];  // e^{+i pi k/64}
    const int tid = threadIdx.x;
    const int img = blockIdx.x >> 4;
    const int c0 = (blockIdx.x & 15) * 16;
    for (int i = tid; i < 96; i += 256) {
        float s, c;
        __sincosf((float)M_PI * (float)i / 64.f, &s, &c);
        tw[i] = make_float2(c, s);
    }
    const float2* zb = Zf + (size_t)img * 32768 + c0;
    for (int it = 0; it < 8; ++it) {
        int idx = it * 256 + tid;
        int rr = idx >> 4, cc = idx & 15;
        buf[0][cc][rr] = zb[rr * 256 + cc];
    }
    __syncthreads();
    int cur = fft4_cols_wavelocal<1, 16>(buf, tw);
    __syncthreads();
    float* ob = out + (size_t)img * 65536 + c0;
    for (int it = 0; it < 8; ++it) {
        int idx = it * 256 + tid;
        int n = idx >> 4, c = idx & 15;
        float2 y = buf[cur][c][n];
        ob[(2 * n) * 256 + c] = y.x;
        ob[(2 * n + 1) * 256 + c] = y.y;
    }
}

extern "C" void kernel_launch(void* const* d_in, const int* in_sizes, int n_in,
                              void* d_out, int out_size, void* d_ws, size_t ws_size,
                              hipStream_t stream) {
    const float* x = (const float*)d_in[0];      // (4,64,128,128)
    const float* k = (const float*)d_in[1];      // (4,64,25,25)
    const float* alpha = (const float*)d_in[2];  // (1,64,1,1)
    float* out = (float*)d_out;                  // (4,64,256,256)

    float2* Fx = (float2*)d_ws;           // 256*16384   = 32 MB (cols 0..64 live)
    float2* Zf = Fx + 256 * 16384;        // 256*128*256 = 64 MB (folded)
    float2* FBtmp = Zf + 256 * 32768;     // 256*25*256  = 13.1 MB

    hipLaunchKernelGGL(k13, dim3(4096 + 256 * 13), dim3(256), 0, stream, x, k, Fx, FBtmp);
    hipLaunchKernelGGL(k2_fft_cols_x, dim3(256 * 5), dim3(256), 0, stream, Fx);
    hipLaunchKernelGGL(k6_fused, dim3(256 * 33), dim3(256), 0, stream, FBtmp, Fx, alpha, Zf);
    hipLaunchKernelGGL(k7_c2r, dim3(4096), dim3(256), 0, stream, Zf, out);
}

// Round 9
// 167.822 us; speedup vs baseline: 2.6725x; 1.0657x over previous
//
#include <hip/hip_runtime.h>
#include <math.h>

// Closed-form pipeline with Hermitian (real-output) symmetry:
//   k13: blocks [0,4096) row-FFT of x (pack-2, cols 0..64); blocks beyond:
//        row FFTs (N=256) of psf rows, 2 rows/block -> FBtmp
//   k2:  column FFT of Fx (wave-local radix-4), cols 0..64
//   k6 fused: on-the-fly column DFT of FBtmp -> 4 FBh rows; M=(1-S1)/(S2+b);
//             FX; radix-4 row IFFT with stage1+stage4 IN REGISTERS;
//             Hermitian fold; write Zf[0..127]
//   k7:  pure 128-pt C2R column IFFT of Zf (wave-local radix-4)
// R7: j-invariant twiddles -> cooperative LDS twiddle tables everywhere.
// R9: radix-4 Stockham; k6 wave-owns-row -> no barriers in FFT loop.
// R10: Fx 2D-Hermitian halving; k2/k7 wave-local columns ([col][130] pad).
// R11: FBh never materialized; k6 does 25-tap dots; mirror rows via (-1)^p.
// R12: LDS overlays (Tt in buf0, stage in buf1) -> 19.5 KB.
// R13: launch_bounds min-waves must stay BELOW live-reg floor: (256,4).
// R14: stage1/stage4 in regs, PHI16, k1+k3 merge. Result: conflicts halved
//   but only -1.7us -> LDS ops were NOT on the issue critical path.
// R15: k6 is pure VALU-issue bound (VALUBusy 81%). Biggest VALU block =
//   DFT section (~600 ops: 4 products + 8 conditional adds per tap).
//   Parity-split FMA accumulators: per tap 8 FMAs (4/row-pair) into
//   even/odd sums of {tx*sx, ty*sy, tx*sy, ty*sx}; the (-1)^p mirror
//   recombination collapses to a one-time 24-op epilogue:
//     aA=(E+O) combos, bA=(E-O) combos.  DFT ~600 -> ~224 VALU.

static __device__ __forceinline__ float2 cmul(float2 a, float2 b) {
    return make_float2(a.x * b.x - a.y * b.y, a.x * b.y + a.y * b.x);
}
static __device__ __forceinline__ float2 cadd(float2 a, float2 b) {
    return make_float2(a.x + b.x, a.y + b.y);
}
static __device__ __forceinline__ float2 csub(float2 a, float2 b) {
    return make_float2(a.x - b.x, a.y - b.y);
}
static __device__ __forceinline__ float2 conjf2(float2 a) {
    return make_float2(a.x, -a.y);
}
static __device__ __forceinline__ int PHI16(int i) { return i + ((i >> 4) << 1); }

// Fill tw[i] = (cos(SIGN*pi*i/HB), sin(SIGN*pi*i/HB)) for i in [0,HB).
template <int HB, int SIGN, int THREADS>
static __device__ __forceinline__ void fill_tw(float2* tw) {
    for (int i = threadIdx.x; i < HB; i += THREADS) {
        float s, c;
        __sincosf((float)SIGN * (float)M_PI * (float)i / (float)HB, &s, &c);
        tw[i] = make_float2(c, s);
    }
}

// ---------------- radix-2 Stockham rows (k13) ----------------
template <int N, int R, int SIGN>
static __device__ __forceinline__ int fft_lds_rows(float2 (&buf)[2][R][N],
                                                   const float2* __restrict__ tw) {
    constexpr int HB = N / 2;
    const int tid = threadIdx.x;
    const int row = tid / HB;
    const int bt = tid % HB;
    int cur = 0, m = 1;
    for (int l = HB; l >= 1; l >>= 1) {
        __syncthreads();
        const int k = bt & (m - 1);
        const float2 w = tw[bt - k];
        float2 a = buf[cur][row][bt];
        float2 b = buf[cur][row][bt + HB];
        float2 d = make_float2(a.x - b.x, a.y - b.y);
        float2 wd = make_float2(w.x * d.x - w.y * d.y, w.x * d.y + w.y * d.x);
        const int o = 2 * bt - k;
        buf[cur ^ 1][row][o] = make_float2(a.x + b.x, a.y + b.y);
        buf[cur ^ 1][row][o + m] = wd;
        cur ^= 1;
        m <<= 1;
    }
    __syncthreads();
    return cur;
}

// ------------- wave-local mixed radix-4/2 128-pt column FFT -------------
template <int SIGN, int NCOL>
static __device__ __forceinline__ int fft4_cols_wavelocal(float2 (&buf)[2][NCOL][130],
                                                          const float2* __restrict__ tw) {
    const int lane = threadIdx.x & 63;
    const int wv = threadIdx.x >> 6;
    const int col = wv * 4 + (lane >> 4);
    const int r = lane & 15;
    int cur = 0, m = 1;
#pragma unroll
    for (int st = 0; st < 3; ++st) {
#pragma unroll
        for (int b = 0; b < 2; ++b) {
            const int bq = r + 16 * b;
            const int k = bq & (m - 1);
            const int jm = bq - k;
            const float2 w1 = tw[jm];
            const float2 w2 = tw[2 * jm];
            const float2 w3 = tw[3 * jm];
            float2 a0 = buf[cur][col][bq];
            float2 a1 = buf[cur][col][bq + 32];
            float2 a2 = buf[cur][col][bq + 64];
            float2 a3 = buf[cur][col][bq + 96];
            float2 s02 = cadd(a0, a2), d02 = csub(a0, a2);
            float2 s13 = cadd(a1, a3), d13 = csub(a1, a3);
            float2 b0 = cadd(s02, s13), b2 = csub(s02, s13);
            float2 b1 = make_float2(d02.x - (float)SIGN * d13.y,
                                    d02.y + (float)SIGN * d13.x);
            float2 b3 = make_float2(d02.x + (float)SIGN * d13.y,
                                    d02.y - (float)SIGN * d13.x);
            const int o = 4 * jm + k;
            buf[cur ^ 1][col][o] = b0;
            buf[cur ^ 1][col][o + m] = cmul(w1, b1);
            buf[cur ^ 1][col][o + 2 * m] = cmul(w2, b2);
            buf[cur ^ 1][col][o + 3 * m] = cmul(w3, b3);
        }
        cur ^= 1;
        m <<= 2;
    }
#pragma unroll
    for (int b = 0; b < 4; ++b) {  // radix-2 tail, m=64, j=0
        const int bt = r + 16 * b;
        float2 a = buf[cur][col][bt];
        float2 bb = buf[cur][col][bt + 64];
        buf[cur ^ 1][col][bt] = cadd(a, bb);
        buf[cur ^ 1][col][bt + 64] = csub(a, bb);
    }
    return cur ^ 1;
}

// K13: merged k1 (x row FFT, pack-2, Hermitian cols 0..64) + k3 (psf row FFT).
// Blocks [0,4096): k1 work. Blocks [4096, 4096+3328): k3, 2 rows/block.
__global__ __launch_bounds__(256) void k13(const float* __restrict__ x,
                                           const float* __restrict__ kin,
                                           float2* __restrict__ Fx,
                                           float2* __restrict__ FBtmp) {
    __shared__ __align__(16) float2 pool[1152];  // max(k1: 1024+64, k3: 1024+128)
    const int tid = threadIdx.x;
    if (blockIdx.x < 4096) {
        using Buf1 = float2[2][4][128];
        Buf1& buf = *reinterpret_cast<Buf1*>(pool);
        float2* tw64m = pool + 1024;
        const int row = tid >> 6;   // pair slot 0..3
        const int t = tid & 63;
        fill_tw<64, -1, 256>(tw64m);
        const int gpair = blockIdx.x * 4 + row;  // img*64 + pr
        const float* r0 = x + (size_t)gpair * 256;
        const float* r1 = r0 + 128;
        const float2 a0 = ((const float2*)r0)[t];
        const float2 a1 = ((const float2*)r1)[t];
        buf[0][row][2 * t].x = a0.x;
        buf[0][row][2 * t].y = a1.x;
        buf[0][row][2 * t + 1].x = a0.y;
        buf[0][row][2 * t + 1].y = a1.y;
        int cur = fft_lds_rows<128, 4, -1>(buf, tw64m);
        float2* d0 = Fx + (size_t)gpair * 256;
        float2* d1 = d0 + 128;
        for (int h = 0; h < 2; ++h) {
            int tt = t + h * 64;
            if (tt > 64) continue;  // Hermitian: cols 65..127 rebuilt in k6
            float2 Zt = buf[cur][row][tt];
            float2 Zm = buf[cur][row][(128 - tt) & 127];
            d0[tt] = make_float2(0.5f * (Zt.x + Zm.x), 0.5f * (Zt.y - Zm.y));
            float ax = Zt.x - Zm.x, ay = Zt.y + Zm.y;
            d1[tt] = make_float2(0.5f * ay, -0.5f * ax);
        }
    } else {
        using Buf3 = float2[2][2][256];
        Buf3& buf = *reinterpret_cast<Buf3*>(pool);
        float2* tw128m = pool + 1024;
        const int b3 = blockIdx.x - 4096;
        const int img = b3 / 13;
        const int sub = b3 % 13;
        const int row = tid >> 7;           // 0..1
        const int t2 = tid & 127;
        int lr = sub * 2 + row;
        const bool live = (lr < 25);
        if (!live) lr = 24;                 // dead group computes garbage, no store
        fill_tw<128, -1, 256>(tw128m);
        const float* krow = kin + img * 625 + lr * 25;
        for (int h = 0; h < 2; ++h) {
            int v = t2 + h * 128;
            int pc = (v + 12) & 255;
            buf[0][row][v] = make_float2(pc < 25 ? krow[pc] : 0.f, 0.f);
        }
        int cur = fft_lds_rows<256, 2, -1>(buf, tw128m);
        if (live) {
            float2* dst = FBtmp + (size_t)img * 6400 + lr * 256;
            dst[t2] = buf[cur][row][t2];
            dst[t2 + 128] = buf[cur][row][t2 + 128];
        }
    }
}

// K2: column FFT of Fx, in place, cols 0..64 only -> 5 tiles of 16.
__global__ __launch_bounds__(256) void k2_fft_cols_x(float2* __restrict__ Fx) {
    __shared__ float2 buf[2][16][130];
    __shared__ float2 tw[96];
    const int tid = threadIdx.x;
    const int img = blockIdx.x / 5;
    const int c0 = (blockIdx.x % 5) * 16;
    for (int i = tid; i < 96; i += 256) {
        float s, c;
        __sincosf(-(float)M_PI * (float)i / 64.f, &s, &c);
        tw[i] = make_float2(c, s);
    }
    float2* base = Fx + (size_t)img * 16384 + c0;
    for (int it = 0; it < 8; ++it) {
        int idx = it * 256 + tid;
        int rr = idx >> 4, cc = idx & 15;
        buf[0][cc][rr] = base[rr * 128 + cc];
    }
    __syncthreads();
    int cur = fft4_cols_wavelocal<-1, 16>(buf, tw);
    __syncthreads();
    for (int it = 0; it < 8; ++it) {
        int idx = it * 256 + tid;
        int rr = idx >> 4, cc = idx & 15;
        base[rr * 128 + cc] = buf[cur][cc][rr];
    }
}

// K6: fused column-DFT + M + FX build + radix-4 row IFFT + Hermitian fold.
// Block = (img, p-pair {pa=2b, pb=2b+1}); wave rs owns one of 4 rows.
__global__ __launch_bounds__(256, 4) void k6_fused(const float2* __restrict__ FBtmp,
                                                   const float2* __restrict__ Fx,
                                                   const float* __restrict__ alpha,
                                                   float2* __restrict__ Zf) {
    __shared__ __align__(16) float2 sm_buf0[4 * 288];  // Tt overlay; FFT buf A
    __shared__ __align__(16) float2 sm_buf1[4 * 288];  // stage overlay; FFT buf B
    __shared__ float2 tw[192];                         // e^{+i pi k/128}, k<192
    float2* Tt = sm_buf0;                // [2][25] flat
    float2* stageF = sm_buf1;            // [4][256] flat
    const int tid = threadIdx.x;
    const int rs = tid >> 6;             // row slot = wave id
    const int q = tid & 63;
    const int img = blockIdx.x / 33;
    const int bq = blockIdx.x % 33;
    const int pa = 2 * bq;
    const int pb = (pa + 1 < 65) ? (pa + 1) : 64;   // last block: pb==pa==64

    const float2* src = FBtmp + (size_t)img * 6400 + tid;
    float2 S[25];
#pragma unroll
    for (int p = 0; p < 25; ++p) S[p] = src[p * 256];

    for (int i = tid; i < 192; i += 256) {
        float s, c;
        __sincosf((float)M_PI * (float)i / 128.f, &s, &c);
        tw[i] = make_float2(c, s);
    }
    {  // DFT twiddles: T_u[p] = W_256^{u(p+244)}
        const float k2pi = -2.f * (float)M_PI / 256.f;
        for (int i = tid; i < 50; i += 256) {
            const int which = i / 25, p = i - which * 25;
            const int u = which ? pb : pa;
            float s, c;
            __sincosf(k2pi * (float)((u * (p + 244)) & 255), &s, &c);
            Tt[which * 25 + p] = make_float2(c, s);
        }
    }
    __syncthreads();  // B0: Tt visible

    // R15: parity-split FMA DFT. Per tap: 8 FMAs. Mirror recombination once.
    {
        float AExx = 0.f, AEyy = 0.f, AExy = 0.f, AEyx = 0.f;
        float AOxx = 0.f, AOyy = 0.f, AOxy = 0.f, AOyx = 0.f;
        float BExx = 0.f, BEyy = 0.f, BExy = 0.f, BEyx = 0.f;
        float BOxx = 0.f, BOyy = 0.f, BOxy = 0.f, BOyx = 0.f;
#pragma unroll
        for (int p = 0; p < 25; ++p) {
            const float2 s = S[p];
            const float2 ta = Tt[p];
            const float2 tb = Tt[25 + p];
            if ((p & 1) == 0) {
                AExx = fmaf(ta.x, s.x, AExx);
                AEyy = fmaf(ta.y, s.y, AEyy);
                AExy = fmaf(ta.x, s.y, AExy);
                AEyx = fmaf(ta.y, s.x, AEyx);
                BExx = fmaf(tb.x, s.x, BExx);
                BEyy = fmaf(tb.y, s.y, BEyy);
                BExy = fmaf(tb.x, s.y, BExy);
                BEyx = fmaf(tb.y, s.x, BEyx);
            } else {
                AOxx = fmaf(ta.x, s.x, AOxx);
                AOyy = fmaf(ta.y, s.y, AOyy);
                AOxy = fmaf(ta.x, s.y, AOxy);
                AOyx = fmaf(ta.y, s.x, AOyx);
                BOxx = fmaf(tb.x, s.x, BOxx);
                BOyy = fmaf(tb.y, s.y, BOyy);
                BOxy = fmaf(tb.x, s.y, BOxy);
                BOyx = fmaf(tb.y, s.x, BOyx);
            }
        }
        // aA = FBh[pa] = sum (ta.s products), bA = FBh[128-pa] via (-1)^p+conj
        stageF[tid] = make_float2((AExx + AOxx) - (AEyy + AOyy),
                                  (AExy + AOxy) + (AEyx + AOyx));
        stageF[256 + tid] = make_float2((AExx - AOxx) + (AEyy - AOyy),
                                        (AExy - AOxy) - (AEyx - AOyx));
        stageF[512 + tid] = make_float2((BExx + BOxx) - (BEyy + BOyy),
                                        (BExy + BOxy) + (BEyx + BOyx));
        stageF[768 + tid] = make_float2((BExx - BOxx) + (BEyy - BOyy),
                                        (BExy - BOxy) - (BEyx - BOyx));
    }
    __syncthreads();  // B1: stage visible (Tt dead; buf0 free)

    const int p = (rs < 2) ? pa : pb;
    const int sb = rs & 2;
    const int u = ((rs & 1) == 0) ? p : (128 - p);   // 0..128
    const int um = u & 127;
    const int msel = (um == p) ? 0 : 1;
    const int mi = sb | msel;
    const int oi = sb | (1 - msel);

    const float ci = tw[um].x, si = -tw[um].y;
    const float b = 1.f / (1.f + __expf(9.f - alpha[img & 63])) + 1e-3f;
    const float scale = 1.f / 65536.f;
    const float2 Di0 = make_float2(1.f + ci, si);
    const float2 Di1 = make_float2(1.f - ci, -si);
    const float2 Du = (u < 128) ? Di0 : Di1;
    float2 X0, X1, X2, X3;  // FX at cols q, q+64, q+128, q+192
#pragma unroll
    for (int h = 0; h < 2; ++h) {
        const int t = q + 64 * h;        // 0..127
        float2 f00 = stageF[mi * 256 + t];
        float2 f01 = stageF[mi * 256 + t + 128];
        float2 f10, f11;
        if (um == 0) {
            f10 = stageF[oi * 256 + t];
            f11 = stageF[oi * 256 + t + 128];
        } else {
            f10 = conjf2(stageF[oi * 256 + ((256 - t) & 255)]);
            f11 = conjf2(stageF[oi * 256 + 128 - t]);
        }
        // Fx stored cols 0..64; mirror t>64: conj(Fx[(128-um)%128][128-t])
        const bool mir = (t > 64);
        const int rr = mir ? ((128 - um) & 127) : um;
        const int cc = mir ? (128 - t) : t;
        float2 fx = Fx[(size_t)img * 16384 + rr * 128 + cc];
        if (mir) fx.y = -fx.y;
        const float cj = tw[t].x, sj = -tw[t].y;
        float2 Dj0 = make_float2(1.f + cj, sj);
        float2 Dj1 = make_float2(1.f - cj, -sj);
        float2 A = cadd(cmul(f00, Dj0), cmul(f01, Dj1));
        float2 Bt = cadd(cmul(f10, Dj0), cmul(f11, Dj1));
        float2 S1 = cadd(cmul(A, Di0), cmul(Bt, Di1));
        S1.x *= 0.25f;
        S1.y *= 0.25f;
        float S2 = 0.25f * (f00.x * f00.x + f00.y * f00.y + f01.x * f01.x + f01.y * f01.y +
                            f10.x * f10.x + f10.y * f10.y + f11.x * f11.x + f11.y * f11.y);
        float inv = 1.f / (S2 + b);
        float2 mm = make_float2((1.f - S1.x) * inv, (-S1.y) * inv);
        float2 c0v = (u < 128) ? f00 : f10;
        float2 c1v = (u < 128) ? f01 : f11;
        float2 t0 = cadd(cmul(conjf2(c0v), mm), cmul(Du, Dj0));
        float2 t1 = cadd(cmul(conjf2(c1v), mm), cmul(Du, Dj1));
        float2 FX0 = cmul(fx, t0);
        float2 FX1 = cmul(fx, t1);
        FX0.x *= scale; FX0.y *= scale;
        FX1.x *= scale; FX1.y *= scale;
        if (h == 0) { X0 = FX0; X2 = FX1; } else { X1 = FX0; X3 = FX1; }
    }

    // FFT stage m=1 in regs (jm=q, k=0): outputs at 4q..4q+3 -> 2x b128.
    {
        float2 s02 = cadd(X0, X2), d02 = csub(X0, X2);
        float2 s13 = cadd(X1, X3), d13 = csub(X1, X3);
        float2 b0 = cadd(s02, s13), b2v = csub(s02, s13);
        float2 b1 = make_float2(d02.x - d13.y, d02.y + d13.x);
        float2 b3 = make_float2(d02.x + d13.y, d02.y - d13.x);
        float2 c1 = cmul(tw[q], b1);
        float2 c2 = cmul(tw[2 * q], b2v);
        float2 c3 = cmul(tw[3 * q], b3);
        float4* dst4 = reinterpret_cast<float4*>(&sm_buf0[rs * 288 + PHI16(4 * q)]);
        dst4[0] = make_float4(b0.x, b0.y, c1.x, c1.y);
        dst4[1] = make_float4(c2.x, c2.y, c3.x, c3.y);
    }
    __syncthreads();  // B2: all stage (buf1) reads done before m=4 writes buf1

    // stage m=4: buf0 -> buf1 (wave-local)
    {
        const int k4 = q & 3, jm = q - k4;
        float2 a0 = sm_buf0[rs * 288 + PHI16(q)];
        float2 a1 = sm_buf0[rs * 288 + PHI16(q + 64)];
        float2 a2 = sm_buf0[rs * 288 + PHI16(q + 128)];
        float2 a3 = sm_buf0[rs * 288 + PHI16(q + 192)];
        float2 s02 = cadd(a0, a2), d02 = csub(a0, a2);
        float2 s13 = cadd(a1, a3), d13 = csub(a1, a3);
        float2 b0 = cadd(s02, s13), b2v = csub(s02, s13);
        float2 b1 = make_float2(d02.x - d13.y, d02.y + d13.x);
        float2 b3 = make_float2(d02.x + d13.y, d02.y - d13.x);
        const int o = 4 * jm + k4;
        sm_buf1[rs * 288 + PHI16(o)] = b0;
        sm_buf1[rs * 288 + PHI16(o + 4)] = cmul(tw[jm], b1);
        sm_buf1[rs * 288 + PHI16(o + 8)] = cmul(tw[2 * jm], b2v);
        sm_buf1[rs * 288 + PHI16(o + 12)] = cmul(tw[3 * jm], b3);
    }
    // stage m=16: buf1 -> buf0 (wave-local, in-order DS)
    {
        const int k16 = q & 15, jm = q - k16;
        float2 a0 = sm_buf1[rs * 288 + PHI16(q)];
        float2 a1 = sm_buf1[rs * 288 + PHI16(q + 64)];
        float2 a2 = sm_buf1[rs * 288 + PHI16(q + 128)];
        float2 a3 = sm_buf1[rs * 288 + PHI16(q + 192)];
        float2 s02 = cadd(a0, a2), d02 = csub(a0, a2);
        float2 s13 = cadd(a1, a3), d13 = csub(a1, a3);
        float2 b0 = cadd(s02, s13), b2v = csub(s02, s13);
        float2 b1 = make_float2(d02.x - d13.y, d02.y + d13.x);
        float2 b3 = make_float2(d02.x + d13.y, d02.y - d13.x);
        const int o = 4 * jm + k16;
        sm_buf0[rs * 288 + PHI16(o)] = b0;
        sm_buf0[rs * 288 + PHI16(o + 16)] = cmul(tw[jm], b1);
        sm_buf0[rs * 288 + PHI16(o + 32)] = cmul(tw[2 * jm], b2v);
        sm_buf0[rs * 288 + PHI16(o + 48)] = cmul(tw[3 * jm], b3);
    }
    // stage m=64 (jm=0, w=1) in regs: outputs at {q, q+64, q+128, q+192}.
    float2 Y0, Y1, Y2, Y3;
    {
        float2 a0 = sm_buf0[rs * 288 + PHI16(q)];
        float2 a1 = sm_buf0[rs * 288 + PHI16(q + 64)];
        float2 a2 = sm_buf0[rs * 288 + PHI16(q + 128)];
        float2 a3 = sm_buf0[rs * 288 + PHI16(q + 192)];
        float2 s02 = cadd(a0, a2), d02 = csub(a0, a2);
        float2 s13 = cadd(a1, a3), d13 = csub(a1, a3);
        Y0 = cadd(s02, s13);
        Y1 = make_float2(d02.x - d13.y, d02.y + d13.x);
        Y2 = csub(s02, s13);
        Y3 = make_float2(d02.x + d13.y, d02.y - d13.x);
    }
    // partner exchange for the fold (buf1 rs-region free after m=16 reads)
    sm_buf1[rs * 288 + PHI16(q)] = Y0;
    sm_buf1[rs * 288 + PHI16(q + 64)] = Y1;
    sm_buf1[rs * 288 + PHI16(q + 128)] = Y2;
    sm_buf1[rs * 288 + PHI16(q + 192)] = Y3;
    __syncthreads();  // B3: cross-wave fold reads rs^1

    // Hermitian fold: Zf[u0] = e + i*w.o, own values in regs, partner via LDS.
    const int u0 = u;
    bool dowrite = ((rs & 1) == 0) ? true : (p > 0 && p < 64);
    if (pb == pa && rs >= 2) dowrite = false;  // last-block dedup
    if (dowrite) {
        const float2 w = tw[u0];
        float2* zb = Zf + (size_t)img * 32768 + (size_t)u0 * 256;
        float2 own[4] = {Y0, Y1, Y2, Y3};
#pragma unroll
        for (int hh = 0; hh < 4; ++hh) {
            const int jj = q + 64 * hh;
            float2 su = own[hh];
            float2 s2 = sm_buf1[(rs ^ 1) * 288 + PHI16(jj)];
            float2 e = make_float2(su.x + s2.x, su.y - s2.y);   // su + conj(s2)
            float2 o_ = make_float2(su.x - s2.x, su.y + s2.y);  // su - conj(s2)
            float2 wo = cmul(w, o_);
            zb[jj] = make_float2(e.x - wo.y, e.y + wo.x);       // e + i*wo
        }
    }
}

// K7: pure C2R column IFFT (wave-local radix-4), 16 cols/block.
__global__ __launch_bounds__(256) void k7_c2r(const float2* __restrict__ Zf,
                                              float* __restrict__ out) {
    __shared__ float2 buf[2][16][130];
    __shared__ float2 tw[96];  // e^{+i pi k/64}
    const int tid = threadIdx.x;
    const int img = blockIdx.x >> 4;
    const int c0 = (blockIdx.x & 15) * 16;
    for (int i = tid; i < 96; i += 256) {
        float s, c;
        __sincosf((float)M_PI * (float)i / 64.f, &s, &c);
        tw[i] = make_float2(c, s);
    }
    const float2* zb = Zf + (size_t)img * 32768 + c0;
    for (int it = 0; it < 8; ++it) {
        int idx = it * 256 + tid;
        int rr = idx >> 4, cc = idx & 15;
        buf[0][cc][rr] = zb[rr * 256 + cc];
    }
    __syncthreads();
    int cur = fft4_cols_wavelocal<1, 16>(buf, tw);
    __syncthreads();
    float* ob = out + (size_t)img * 65536 + c0;
    for (int it = 0; it < 8; ++it) {
        int idx = it * 256 + tid;
        int n = idx >> 4, c = idx & 15;
        float2 y = buf[cur][c][n];
        ob[(2 * n) * 256 + c] = y.x;
        ob[(2 * n + 1) * 256 + c] = y.y;
    }
}

extern "C" void kernel_launch(void* const* d_in, const int* in_sizes, int n_in,
                              void* d_out, int out_size, void* d_ws, size_t ws_size,
                              hipStream_t stream) {
    const float* x = (const float*)d_in[0];      // (4,64,128,128)
    const float* k = (const float*)d_in[1];      // (4,64,25,25)
    const float* alpha = (const float*)d_in[2];  // (1,64,1,1)
    float* out = (float*)d_out;                  // (4,64,256,256)

    float2* Fx = (float2*)d_ws;           // 256*16384   = 32 MB (cols 0..64 live)
    float2* Zf = Fx + 256 * 16384;        // 256*128*256 = 64 MB (folded)
    float2* FBtmp = Zf + 256 * 32768;     // 256*25*256  = 13.1 MB

    hipLaunchKernelGGL(k13, dim3(4096 + 256 * 13), dim3(256), 0, stream, x, k, Fx, FBtmp);
    hipLaunchKernelGGL(k2_fft_cols_x, dim3(256 * 5), dim3(256), 0, stream, Fx);
    hipLaunchKernelGGL(k6_fused, dim3(256 * 33), dim3(256), 0, stream, FBtmp, Fx, alpha, Zf);
    hipLaunchKernelGGL(k7_c2r, dim3(4096), dim3(256), 0, stream, Zf, out);
}

// Round 10
// 166.723 us; speedup vs baseline: 2.6901x; 1.0066x over previous
//
#include <hip/hip_runtime.h>
#include <math.h>

// Closed-form pipeline with Hermitian (real-output) symmetry:
//   k13: blocks [0,4096) row-FFT of x (pack-2, cols 0..64, WAVE-LOCAL
//        barrier-free stages); blocks beyond: psf row FFTs (N=256),
//        4 rows/block wave-per-row barrier-free -> FBtmp
//   k2:  column FFT of Fx (wave-local radix-4), cols 0..64
//   k6 fused: on-the-fly column DFT of FBtmp -> 4 FBh rows; M; FX;
//             radix-4 row IFFT (stage1+stage4 in regs); Hermitian fold
//   k7:  pure 128-pt C2R column IFFT of Zf (wave-local radix-4)
// R7: j-invariant twiddles -> cooperative LDS twiddle tables.
// R9: wave-owns-row FFT stages need NO barriers (in-order DS within wave).
// R10: Fx 2D-Hermitian halving; k2/k7 wave-local columns.
// R11: FBh never materialized; 25-tap dots; mirror rows via (-1)^p.
// R12: LDS overlays -> 19.5 KB. R13: launch_bounds min-waves below reg floor.
// R14: stage1/stage4 in regs, PHI16. R15: parity-split FMA DFT (k6 70->51.6).
// R16: barrier diet: k13 stages barrier-free (8 barriers -> 1, tw only);
//   k6 Tt made PER-WAVE (own buf0 slot, wave-local) -> B0 deleted (4->3);
//   mm = (4-S1')/(S2'+4b) folds the 0.25 normalizations away.

static __device__ __forceinline__ float2 cmul(float2 a, float2 b) {
    return make_float2(a.x * b.x - a.y * b.y, a.x * b.y + a.y * b.x);
}
static __device__ __forceinline__ float2 cadd(float2 a, float2 b) {
    return make_float2(a.x + b.x, a.y + b.y);
}
static __device__ __forceinline__ float2 csub(float2 a, float2 b) {
    return make_float2(a.x - b.x, a.y - b.y);
}
static __device__ __forceinline__ float2 conjf2(float2 a) {
    return make_float2(a.x, -a.y);
}
static __device__ __forceinline__ int PHI16(int i) { return i + ((i >> 4) << 1); }

// ------------- wave-local mixed radix-4/2 128-pt column FFT -------------
template <int SIGN, int NCOL>
static __device__ __forceinline__ int fft4_cols_wavelocal(float2 (&buf)[2][NCOL][130],
                                                          const float2* __restrict__ tw) {
    const int lane = threadIdx.x & 63;
    const int wv = threadIdx.x >> 6;
    const int col = wv * 4 + (lane >> 4);
    const int r = lane & 15;
    int cur = 0, m = 1;
#pragma unroll
    for (int st = 0; st < 3; ++st) {
#pragma unroll
        for (int b = 0; b < 2; ++b) {
            const int bq = r + 16 * b;
            const int k = bq & (m - 1);
            const int jm = bq - k;
            const float2 w1 = tw[jm];
            const float2 w2 = tw[2 * jm];
            const float2 w3 = tw[3 * jm];
            float2 a0 = buf[cur][col][bq];
            float2 a1 = buf[cur][col][bq + 32];
            float2 a2 = buf[cur][col][bq + 64];
            float2 a3 = buf[cur][col][bq + 96];
            float2 s02 = cadd(a0, a2), d02 = csub(a0, a2);
            float2 s13 = cadd(a1, a3), d13 = csub(a1, a3);
            float2 b0 = cadd(s02, s13), b2 = csub(s02, s13);
            float2 b1 = make_float2(d02.x - (float)SIGN * d13.y,
                                    d02.y + (float)SIGN * d13.x);
            float2 b3 = make_float2(d02.x + (float)SIGN * d13.y,
                                    d02.y - (float)SIGN * d13.x);
            const int o = 4 * jm + k;
            buf[cur ^ 1][col][o] = b0;
            buf[cur ^ 1][col][o + m] = cmul(w1, b1);
            buf[cur ^ 1][col][o + 2 * m] = cmul(w2, b2);
            buf[cur ^ 1][col][o + 3 * m] = cmul(w3, b3);
        }
        cur ^= 1;
        m <<= 2;
    }
#pragma unroll
    for (int b = 0; b < 4; ++b) {  // radix-2 tail, m=64, j=0
        const int bt = r + 16 * b;
        float2 a = buf[cur][col][bt];
        float2 bb = buf[cur][col][bt + 64];
        buf[cur ^ 1][col][bt] = cadd(a, bb);
        buf[cur ^ 1][col][bt + 64] = csub(a, bb);
    }
    return cur ^ 1;
}

// K13: merged k1 (x row FFT) + k3 (psf row FFT), both wave-per-row,
// barrier-free stages (R16). One barrier total (tw table publish).
// Blocks [0,4096): k1. Blocks [4096, 4096+1792): k3, 4 rows/block.
__global__ __launch_bounds__(256) void k13(const float* __restrict__ x,
                                           const float* __restrict__ kin,
                                           float2* __restrict__ Fx,
                                           float2* __restrict__ FBtmp) {
    __shared__ __align__(16) float2 pool[2176];  // k1: 1024+64; k3: 2048+128
    const int tid = threadIdx.x;
    const int rs = tid >> 6;
    const int lane = tid & 63;
    if (blockIdx.x < 4096) {
        float2* tw = pool + 1024;  // 64 entries, e^{-i pi k/64}
        for (int i = tid; i < 64; i += 256) {
            float s, c;
            __sincosf(-(float)M_PI * (float)i / 64.f, &s, &c);
            tw[i] = make_float2(c, s);
        }
        const int gpair = blockIdx.x * 4 + rs;  // img*64 + pr
        const float* r0 = x + (size_t)gpair * 256;
        const float* r1 = r0 + 128;
        const float2 a0 = ((const float2*)r0)[lane];
        const float2 a1 = ((const float2*)r1)[lane];
        float2* R = pool + rs * 128;            // cur=0 slot for this wave
        R[2 * lane] = make_float2(a0.x, a1.x);
        R[2 * lane + 1] = make_float2(a0.y, a1.y);
        __syncthreads();  // tw visible (row data is wave-local already)
        int cur = 0, m = 1;
        for (int l = 64; l >= 1; l >>= 1) {   // 7 stages, barrier-free
            float2* Bc = pool + cur * 512 + rs * 128;
            float2* Bn = pool + (cur ^ 1) * 512 + rs * 128;
            const int k = lane & (m - 1);
            const float2 w = tw[lane - k];
            float2 a = Bc[lane];
            float2 b = Bc[lane + 64];
            float2 d = csub(a, b);
            const int o = 2 * lane - k;
            Bn[o] = cadd(a, b);
            Bn[o + m] = cmul(w, d);
            cur ^= 1;
            m <<= 1;
        }
        float2* Bc = pool + cur * 512 + rs * 128;
        float2* d0 = Fx + (size_t)gpair * 256;
        float2* d1 = d0 + 128;
        for (int h = 0; h < 2; ++h) {
            int tt = lane + h * 64;
            if (tt > 64) continue;  // Hermitian: cols 65..127 rebuilt in k6
            float2 Zt = Bc[tt];
            float2 Zm = Bc[(128 - tt) & 127];
            d0[tt] = make_float2(0.5f * (Zt.x + Zm.x), 0.5f * (Zt.y - Zm.y));
            float ax = Zt.x - Zm.x, ay = Zt.y + Zm.y;
            d1[tt] = make_float2(0.5f * ay, -0.5f * ax);
        }
    } else {
        float2* tw = pool + 2048;  // 128 entries, e^{-i pi k/128}
        for (int i = tid; i < 128; i += 256) {
            float s, c;
            __sincosf(-(float)M_PI * (float)i / 128.f, &s, &c);
            tw[i] = make_float2(c, s);
        }
        const int b3 = blockIdx.x - 4096;
        const int img = b3 / 7;
        const int sub = b3 % 7;
        int lr = sub * 4 + rs;
        const bool live = (lr < 25);
        if (!live) lr = 24;  // dead wave computes garbage, no store
        const float* krow = kin + img * 625 + lr * 25;
        float2* R = pool + rs * 256;
#pragma unroll
        for (int h = 0; h < 4; ++h) {
            int v = lane + h * 64;
            int pc = (v + 12) & 255;
            R[v] = make_float2(pc < 25 ? krow[pc] : 0.f, 0.f);
        }
        __syncthreads();  // tw visible
        int cur = 0, m = 1;
        for (int l = 128; l >= 1; l >>= 1) {  // 8 stages, barrier-free
            float2* Bc = pool + cur * 1024 + rs * 256;
            float2* Bn = pool + (cur ^ 1) * 1024 + rs * 256;
#pragma unroll
            for (int b = 0; b < 2; ++b) {
                const int bt = lane + 64 * b;
                const int k = bt & (m - 1);
                const float2 w = tw[bt - k];
                float2 a = Bc[bt];
                float2 bb = Bc[bt + 128];
                float2 d = csub(a, bb);
                const int o = 2 * bt - k;
                Bn[o] = cadd(a, bb);
                Bn[o + m] = cmul(w, d);
            }
            cur ^= 1;
            m <<= 1;
        }
        if (live) {
            float2* Bc = pool + cur * 1024 + rs * 256;
            float2* dst = FBtmp + (size_t)img * 6400 + lr * 256;
#pragma unroll
            for (int h = 0; h < 4; ++h) {
                int v = lane + h * 64;
                dst[v] = Bc[v];
            }
        }
    }
}

// K2: column FFT of Fx, in place, cols 0..64 only -> 5 tiles of 16.
__global__ __launch_bounds__(256) void k2_fft_cols_x(float2* __restrict__ Fx) {
    __shared__ float2 buf[2][16][130];
    __shared__ float2 tw[96];
    const int tid = threadIdx.x;
    const int img = blockIdx.x / 5;
    const int c0 = (blockIdx.x % 5) * 16;
    for (int i = tid; i < 96; i += 256) {
        float s, c;
        __sincosf(-(float)M_PI * (float)i / 64.f, &s, &c);
        tw[i] = make_float2(c, s);
    }
    float2* base = Fx + (size_t)img * 16384 + c0;
    for (int it = 0; it < 8; ++it) {
        int idx = it * 256 + tid;
        int rr = idx >> 4, cc = idx & 15;
        buf[0][cc][rr] = base[rr * 128 + cc];
    }
    __syncthreads();
    int cur = fft4_cols_wavelocal<-1, 16>(buf, tw);
    __syncthreads();
    for (int it = 0; it < 8; ++it) {
        int idx = it * 256 + tid;
        int rr = idx >> 4, cc = idx & 15;
        base[rr * 128 + cc] = buf[cur][cc][rr];
    }
}

// K6: fused column-DFT + M + FX build + radix-4 row IFFT + Hermitian fold.
// Block = (img, p-pair {pa=2b, pb=2b+1}); wave rs owns one of 4 rows.
// R16: Tt per-wave (own buf0 slot) -> no barrier before DFT (3 barriers).
__global__ __launch_bounds__(256, 4) void k6_fused(const float2* __restrict__ FBtmp,
                                                   const float2* __restrict__ Fx,
                                                   const float* __restrict__ alpha,
                                                   float2* __restrict__ Zf) {
    __shared__ __align__(16) float2 sm_buf0[4 * 288];  // per-wave Tt; FFT buf A
    __shared__ __align__(16) float2 sm_buf1[4 * 288];  // stage overlay; FFT buf B
    __shared__ float2 tw[192];                         // e^{+i pi k/128}, k<192
    float2* stageF = sm_buf1;            // [4][256] flat
    const int tid = threadIdx.x;
    const int rs = tid >> 6;             // row slot = wave id
    const int q = tid & 63;
    const int img = blockIdx.x / 33;
    const int bq = blockIdx.x % 33;
    const int pa = 2 * bq;
    const int pb = (pa + 1 < 65) ? (pa + 1) : 64;   // last block: pb==pa==64

    const float2* src = FBtmp + (size_t)img * 6400 + tid;
    float2 S[25];
#pragma unroll
    for (int p = 0; p < 25; ++p) S[p] = src[p * 256];

    for (int i = tid; i < 192; i += 256) {
        float s, c;
        __sincosf((float)M_PI * (float)i / 128.f, &s, &c);
        tw[i] = make_float2(c, s);
    }
    // Per-wave DFT twiddles (R16): wave rs fills its OWN 50-entry copy at
    // sm_buf0[rs*288 .. +49] -> purely wave-local, no barrier needed.
    float2* Ttw = sm_buf0 + rs * 288;
    if (q < 50) {
        const int which = q >= 25;
        const int p = which ? (q - 25) : q;
        const int u = which ? pb : pa;
        const float k2pi = -2.f * (float)M_PI / 256.f;
        float s, c;
        __sincosf(k2pi * (float)((u * (p + 244)) & 255), &s, &c);
        Ttw[q] = make_float2(c, s);
    }

    // R15: parity-split FMA DFT. Per tap: 8 FMAs. Mirror recombination once.
    {
        float AExx = 0.f, AEyy = 0.f, AExy = 0.f, AEyx = 0.f;
        float AOxx = 0.f, AOyy = 0.f, AOxy = 0.f, AOyx = 0.f;
        float BExx = 0.f, BEyy = 0.f, BExy = 0.f, BEyx = 0.f;
        float BOxx = 0.f, BOyy = 0.f, BOxy = 0.f, BOyx = 0.f;
#pragma unroll
        for (int p = 0; p < 25; ++p) {
            const float2 s = S[p];
            const float2 ta = Ttw[p];
            const float2 tb = Ttw[25 + p];
            if ((p & 1) == 0) {
                AExx = fmaf(ta.x, s.x, AExx);
                AEyy = fmaf(ta.y, s.y, AEyy);
                AExy = fmaf(ta.x, s.y, AExy);
                AEyx = fmaf(ta.y, s.x, AEyx);
                BExx = fmaf(tb.x, s.x, BExx);
                BEyy = fmaf(tb.y, s.y, BEyy);
                BExy = fmaf(tb.x, s.y, BExy);
                BEyx = fmaf(tb.y, s.x, BEyx);
            } else {
                AOxx = fmaf(ta.x, s.x, AOxx);
                AOyy = fmaf(ta.y, s.y, AOyy);
                AOxy = fmaf(ta.x, s.y, AOxy);
                AOyx = fmaf(ta.y, s.x, AOyx);
                BOxx = fmaf(tb.x, s.x, BOxx);
                BOyy = fmaf(tb.y, s.y, BOyy);
                BOxy = fmaf(tb.x, s.y, BOxy);
                BOyx = fmaf(tb.y, s.x, BOyx);
            }
        }
        stageF[tid] = make_float2((AExx + AOxx) - (AEyy + AOyy),
                                  (AExy + AOxy) + (AEyx + AOyx));
        stageF[256 + tid] = make_float2((AExx - AOxx) + (AEyy - AOyy),
                                        (AExy - AOxy) - (AEyx - AOyx));
        stageF[512 + tid] = make_float2((BExx + BOxx) - (BEyy + BOyy),
                                        (BExy + BOxy) + (BEyx + BOyx));
        stageF[768 + tid] = make_float2((BExx - BOxx) + (BEyy - BOyy),
                                        (BExy - BOxy) - (BEyx - BOyx));
    }
    __syncthreads();  // B1: stage + tw visible

    const int p = (rs < 2) ? pa : pb;
    const int sb = rs & 2;
    const int u = ((rs & 1) == 0) ? p : (128 - p);   // 0..128
    const int um = u & 127;
    const int msel = (um == p) ? 0 : 1;
    const int mi = sb | msel;
    const int oi = sb | (1 - msel);

    const float ci = tw[um].x, si = -tw[um].y;
    const float b4 = 4.f / (1.f + __expf(9.f - alpha[img & 63])) + 4e-3f;  // 4b
    const float scale = 1.f / 65536.f;
    const float2 Di0 = make_float2(1.f + ci, si);
    const float2 Di1 = make_float2(1.f - ci, -si);
    const float2 Du = (u < 128) ? Di0 : Di1;
    float2 X0, X1, X2, X3;  // FX at cols q, q+64, q+128, q+192
#pragma unroll
    for (int h = 0; h < 2; ++h) {
        const int t = q + 64 * h;        // 0..127
        float2 f00 = stageF[mi * 256 + t];
        float2 f01 = stageF[mi * 256 + t + 128];
        float2 f10, f11;
        if (um == 0) {
            f10 = stageF[oi * 256 + t];
            f11 = stageF[oi * 256 + t + 128];
        } else {
            f10 = conjf2(stageF[oi * 256 + ((256 - t) & 255)]);
            f11 = conjf2(stageF[oi * 256 + 128 - t]);
        }
        // Fx stored cols 0..64; mirror t>64: conj(Fx[(128-um)%128][128-t])
        const bool mir = (t > 64);
        const int rr = mir ? ((128 - um) & 127) : um;
        const int cc = mir ? (128 - t) : t;
        float2 fx = Fx[(size_t)img * 16384 + rr * 128 + cc];
        if (mir) fx.y = -fx.y;
        const float cj = tw[t].x, sj = -tw[t].y;
        float2 Dj0 = make_float2(1.f + cj, sj);
        float2 Dj1 = make_float2(1.f - cj, -sj);
        // S1' = 4*S1, S2' = 4*S2; mm = (4 - S1')/(S2' + 4b)  (R16 algebra)
        float2 A = cadd(cmul(f00, Dj0), cmul(f01, Dj1));
        float2 Bt = cadd(cmul(f10, Dj0), cmul(f11, Dj1));
        float2 S1 = cadd(cmul(A, Di0), cmul(Bt, Di1));
        float S2 = f00.x * f00.x + f00.y * f00.y + f01.x * f01.x + f01.y * f01.y +
                   f10.x * f10.x + f10.y * f10.y + f11.x * f11.x + f11.y * f11.y;
        float inv = 1.f / (S2 + b4);
        float2 mm = make_float2((4.f - S1.x) * inv, (-S1.y) * inv);
        float2 c0v = (u < 128) ? f00 : f10;
        float2 c1v = (u < 128) ? f01 : f11;
        float2 t0 = cadd(cmul(conjf2(c0v), mm), cmul(Du, Dj0));
        float2 t1 = cadd(cmul(conjf2(c1v), mm), cmul(Du, Dj1));
        float2 FX0 = cmul(fx, t0);
        float2 FX1 = cmul(fx, t1);
        FX0.x *= scale; FX0.y *= scale;
        FX1.x *= scale; FX1.y *= scale;
        if (h == 0) { X0 = FX0; X2 = FX1; } else { X1 = FX0; X3 = FX1; }
    }

    // FFT stage m=1 in regs (jm=q, k=0): outputs at 4q..4q+3 -> 2x b128.
    {
        float2 s02 = cadd(X0, X2), d02 = csub(X0, X2);
        float2 s13 = cadd(X1, X3), d13 = csub(X1, X3);
        float2 b0 = cadd(s02, s13), b2v = csub(s02, s13);
        float2 b1 = make_float2(d02.x - d13.y, d02.y + d13.x);
        float2 b3 = make_float2(d02.x + d13.y, d02.y - d13.x);
        float2 c1 = cmul(tw[q], b1);
        float2 c2 = cmul(tw[2 * q], b2v);
        float2 c3 = cmul(tw[3 * q], b3);
        float4* dst4 = reinterpret_cast<float4*>(&sm_buf0[rs * 288 + PHI16(4 * q)]);
        dst4[0] = make_float4(b0.x, b0.y, c1.x, c1.y);
        dst4[1] = make_float4(c2.x, c2.y, c3.x, c3.y);
    }
    __syncthreads();  // B2: all stage (buf1) reads done before m=4 writes buf1

    // stage m=4: buf0 -> buf1 (wave-local)
    {
        const int k4 = q & 3, jm = q - k4;
        float2 a0 = sm_buf0[rs * 288 + PHI16(q)];
        float2 a1 = sm_buf0[rs * 288 + PHI16(q + 64)];
        float2 a2 = sm_buf0[rs * 288 + PHI16(q + 128)];
        float2 a3 = sm_buf0[rs * 288 + PHI16(q + 192)];
        float2 s02 = cadd(a0, a2), d02 = csub(a0, a2);
        float2 s13 = cadd(a1, a3), d13 = csub(a1, a3);
        float2 b0 = cadd(s02, s13), b2v = csub(s02, s13);
        float2 b1 = make_float2(d02.x - d13.y, d02.y + d13.x);
        float2 b3 = make_float2(d02.x + d13.y, d02.y - d13.x);
        const int o = 4 * jm + k4;
        sm_buf1[rs * 288 + PHI16(o)] = b0;
        sm_buf1[rs * 288 + PHI16(o + 4)] = cmul(tw[jm], b1);
        sm_buf1[rs * 288 + PHI16(o + 8)] = cmul(tw[2 * jm], b2v);
        sm_buf1[rs * 288 + PHI16(o + 12)] = cmul(tw[3 * jm], b3);
    }
    // stage m=16: buf1 -> buf0 (wave-local, in-order DS)
    {
        const int k16 = q & 15, jm = q - k16;
        float2 a0 = sm_buf1[rs * 288 + PHI16(q)];
        float2 a1 = sm_buf1[rs * 288 + PHI16(q + 64)];
        float2 a2 = sm_buf1[rs * 288 + PHI16(q + 128)];
        float2 a3 = sm_buf1[rs * 288 + PHI16(q + 192)];
        float2 s02 = cadd(a0, a2), d02 = csub(a0, a2);
        float2 s13 = cadd(a1, a3), d13 = csub(a1, a3);
        float2 b0 = cadd(s02, s13), b2v = csub(s02, s13);
        float2 b1 = make_float2(d02.x - d13.y, d02.y + d13.x);
        float2 b3 = make_float2(d02.x + d13.y, d02.y - d13.x);
        const int o = 4 * jm + k16;
        sm_buf0[rs * 288 + PHI16(o)] = b0;
        sm_buf0[rs * 288 + PHI16(o + 16)] = cmul(tw[jm], b1);
        sm_buf0[rs * 288 + PHI16(o + 32)] = cmul(tw[2 * jm], b2v);
        sm_buf0[rs * 288 + PHI16(o + 48)] = cmul(tw[3 * jm], b3);
    }
    // stage m=64 (jm=0, w=1) in regs: outputs at {q, q+64, q+128, q+192}.
    float2 Y0, Y1, Y2, Y3;
    {
        float2 a0 = sm_buf0[rs * 288 + PHI16(q)];
        float2 a1 = sm_buf0[rs * 288 + PHI16(q + 64)];
        float2 a2 = sm_buf0[rs * 288 + PHI16(q + 128)];
        float2 a3 = sm_buf0[rs * 288 + PHI16(q + 192)];
        float2 s02 = cadd(a0, a2), d02 = csub(a0, a2);
        float2 s13 = cadd(a1, a3), d13 = csub(a1, a3);
        Y0 = cadd(s02, s13);
        Y1 = make_float2(d02.x - d13.y, d02.y + d13.x);
        Y2 = csub(s02, s13);
        Y3 = make_float2(d02.x + d13.y, d02.y - d13.x);
    }
    // partner exchange for the fold (buf1 rs-region free after m=16 reads)
    sm_buf1[rs * 288 + PHI16(q)] = Y0;
    sm_buf1[rs * 288 + PHI16(q + 64)] = Y1;
    sm_buf1[rs * 288 + PHI16(q + 128)] = Y2;
    sm_buf1[rs * 288 + PHI16(q + 192)] = Y3;
    __syncthreads();  // B3: cross-wave fold reads rs^1

    // Hermitian fold: Zf[u0] = e + i*w.o, own values in regs, partner via LDS.
    const int u0 = u;
    bool dowrite = ((rs & 1) == 0) ? true : (p > 0 && p < 64);
    if (pb == pa && rs >= 2) dowrite = false;  // last-block dedup
    if (dowrite) {
        const float2 w = tw[u0];
        float2* zb = Zf + (size_t)img * 32768 + (size_t)u0 * 256;
        float2 own[4] = {Y0, Y1, Y2, Y3};
#pragma unroll
        for (int hh = 0; hh < 4; ++hh) {
            const int jj = q + 64 * hh;
            float2 su = own[hh];
            float2 s2 = sm_buf1[(rs ^ 1) * 288 + PHI16(jj)];
            float2 e = make_float2(su.x + s2.x, su.y - s2.y);   // su + conj(s2)
            float2 o_ = make_float2(su.x - s2.x, su.y + s2.y);  // su - conj(s2)
            float2 wo = cmul(w, o_);
            zb[jj] = make_float2(e.x - wo.y, e.y + wo.x);       // e + i*wo
        }
    }
}

// K7: pure C2R column IFFT (wave-local radix-4), 16 cols/block.
__global__ __launch_bounds__(256) void k7_c2r(const float2* __restrict__ Zf,
                                              float* __restrict__ out) {
    __shared__ float2 buf[2][16][130];
    __shared__ float2 tw[96];  // e^{+i pi k/64}
    const int tid = threadIdx.x;
    const int img = blockIdx.x >> 4;
    const int c0 = (blockIdx.x & 15) * 16;
    for (int i = tid; i < 96; i += 256) {
        float s, c;
        __sincosf((float)M_PI * (float)i / 64.f, &s, &c);
        tw[i] = make_float2(c, s);
    }
    const float2* zb = Zf + (size_t)img * 32768 + c0;
    for (int it = 0; it < 8; ++it) {
        int idx = it * 256 + tid;
        int rr = idx >> 4, cc = idx & 15;
        buf[0][cc][rr] = zb[rr * 256 + cc];
    }
    __syncthreads();
    int cur = fft4_cols_wavelocal<1, 16>(buf, tw);
    __syncthreads();
    float* ob = out + (size_t)img * 65536 + c0;
    for (int it = 0; it < 8; ++it) {
        int idx = it * 256 + tid;
        int n = idx >> 4, c = idx & 15;
        float2 y = buf[cur][c][n];
        ob[(2 * n) * 256 + c] = y.x;
        ob[(2 * n + 1) * 256 + c] = y.y;
    }
}

extern "C" void kernel_launch(void* const* d_in, const int* in_sizes, int n_in,
                              void* d_out, int out_size, void* d_ws, size_t ws_size,
                              hipStream_t stream) {
    const float* x = (const float*)d_in[0];      // (4,64,128,128)
    const float* k = (const float*)d_in[1];      // (4,64,25,25)
    const float* alpha = (const float*)d_in[2];  // (1,64,1,1)
    float* out = (float*)d_out;                  // (4,64,256,256)

    float2* Fx = (float2*)d_ws;           // 256*16384   = 32 MB (cols 0..64 live)
    float2* Zf = Fx + 256 * 16384;        // 256*128*256 = 64 MB (folded)
    float2* FBtmp = Zf + 256 * 32768;     // 256*25*256  = 13.1 MB

    hipLaunchKernelGGL(k13, dim3(4096 + 256 * 7), dim3(256), 0, stream, x, k, Fx, FBtmp);
    hipLaunchKernelGGL(k2_fft_cols_x, dim3(256 * 5), dim3(256), 0, stream, Fx);
    hipLaunchKernelGGL(k6_fused, dim3(256 * 33), dim3(256), 0, stream, FBtmp, Fx, alpha, Zf);
    hipLaunchKernelGGL(k7_c2r, dim3(4096), dim3(256), 0, stream, Zf, out);
}

// Round 11
// 165.190 us; speedup vs baseline: 2.7151x; 1.0093x over previous
//
#include <hip/hip_runtime.h>
#include <math.h>

// Closed-form pipeline with Hermitian (real-output) symmetry:
//   k13: blocks [0,4096) row-FFT of x (pack-2, cols 0..64, wave-local
//        barrier-free stages); blocks beyond: psf row FFTs -> FBtmp
//   k2:  column FFT of Fx (IN-PLACE radix-4, 100% occupancy), cols 0..64
//   k6 fused: on-the-fly column DFT of FBtmp -> 4 FBh rows; M; FX;
//             radix-4 row IFFT (stage1+stage4 in regs); Hermitian fold
//   k7:  pure 128-pt C2R column IFFT of Zf (IN-PLACE radix-4)
// R7: j-invariant twiddles -> LDS tables. R9: wave-owns-row = barrier-free.
// R10: Fx 2D-Hermitian halving. R11: FBh never materialized (25-tap dots).
// R12: LDS overlays -> 19.5 KB. R13: min-waves below reg floor (spill!).
// R14: stage1/stage4 in regs, PHI16. R15: parity-split FMA DFT (70->51.6).
// R16: k13 barrier-free; per-wave Tt; folded normalization.
// R17: (a) k2/k7 were 50%-occupancy streamers (33 KB dbuf -> 4 blk/CU).
//   In-place Stockham (read->barrier->write; stages are bijections; tail is
//   thread-local) halves LDS -> 17.4 KB -> 8 blk/CU = 32 waves = 100%.
//   (b) k6: Fx/alpha loads hoisted ABOVE the DFT (they were barrier-pinned
//   after B1); ~500cy latency now hides under the 200-FMA DFT.

static __device__ __forceinline__ float2 cmul(float2 a, float2 b) {
    return make_float2(a.x * b.x - a.y * b.y, a.x * b.y + a.y * b.x);
}
static __device__ __forceinline__ float2 cadd(float2 a, float2 b) {
    return make_float2(a.x + b.x, a.y + b.y);
}
static __device__ __forceinline__ float2 csub(float2 a, float2 b) {
    return make_float2(a.x - b.x, a.y - b.y);
}
static __device__ __forceinline__ float2 conjf2(float2 a) {
    return make_float2(a.x, -a.y);
}
static __device__ __forceinline__ int PHI16(int i) { return i + ((i >> 4) << 1); }

// -------- in-place wave-tile mixed radix-4/2 128-pt column FFT (R17) --------
// buf[NCOL][130]; each wave handles 4 cols (16 lanes/col). Stages read all
// inputs to regs, barrier, write in place, barrier. Radix-2 tail is
// thread-local (reads==writes per thread) -> no barrier.
template <int SIGN, int NCOL>
static __device__ __forceinline__ void fft4_cols_inplace(float2 (&buf)[NCOL][130],
                                                         const float2* __restrict__ tw) {
    const int lane = threadIdx.x & 63;
    const int wv = threadIdx.x >> 6;
    const int col = wv * 4 + (lane >> 4);
    const int r = lane & 15;
    int m = 1;
#pragma unroll
    for (int st = 0; st < 3; ++st) {
        float2 o0[2], o1[2], o2[2], o3[2];
        int ob_[2];
#pragma unroll
        for (int b = 0; b < 2; ++b) {
            const int bq = r + 16 * b;
            const int k = bq & (m - 1);
            const int jm = bq - k;
            float2 a0 = buf[col][bq];
            float2 a1 = buf[col][bq + 32];
            float2 a2 = buf[col][bq + 64];
            float2 a3 = buf[col][bq + 96];
            float2 s02 = cadd(a0, a2), d02 = csub(a0, a2);
            float2 s13 = cadd(a1, a3), d13 = csub(a1, a3);
            o0[b] = cadd(s02, s13);
            float2 b2 = csub(s02, s13);
            float2 b1 = make_float2(d02.x - (float)SIGN * d13.y,
                                    d02.y + (float)SIGN * d13.x);
            float2 b3 = make_float2(d02.x + (float)SIGN * d13.y,
                                    d02.y - (float)SIGN * d13.x);
            o1[b] = cmul(tw[jm], b1);
            o2[b] = cmul(tw[2 * jm], b2);
            o3[b] = cmul(tw[3 * jm], b3);
            ob_[b] = 4 * jm + k;
        }
        __syncthreads();
#pragma unroll
        for (int b = 0; b < 2; ++b) {
            const int o = ob_[b];
            buf[col][o] = o0[b];
            buf[col][o + m] = o1[b];
            buf[col][o + 2 * m] = o2[b];
            buf[col][o + 3 * m] = o3[b];
        }
        __syncthreads();
        m <<= 2;
    }
#pragma unroll
    for (int b = 0; b < 4; ++b) {  // radix-2 tail, m=64, j=0, thread-local
        const int bt = r + 16 * b;
        float2 a = buf[col][bt];
        float2 bb = buf[col][bt + 64];
        buf[col][bt] = cadd(a, bb);
        buf[col][bt + 64] = csub(a, bb);
    }
}

// K13: merged k1 (x row FFT) + k3 (psf row FFT), both wave-per-row,
// barrier-free stages (R16). One barrier total (tw table publish).
__global__ __launch_bounds__(256) void k13(const float* __restrict__ x,
                                           const float* __restrict__ kin,
                                           float2* __restrict__ Fx,
                                           float2* __restrict__ FBtmp) {
    __shared__ __align__(16) float2 pool[2176];  // k1: 1024+64; k3: 2048+128
    const int tid = threadIdx.x;
    const int rs = tid >> 6;
    const int lane = tid & 63;
    if (blockIdx.x < 4096) {
        float2* tw = pool + 1024;  // 64 entries, e^{-i pi k/64}
        for (int i = tid; i < 64; i += 256) {
            float s, c;
            __sincosf(-(float)M_PI * (float)i / 64.f, &s, &c);
            tw[i] = make_float2(c, s);
        }
        const int gpair = blockIdx.x * 4 + rs;  // img*64 + pr
        const float* r0 = x + (size_t)gpair * 256;
        const float* r1 = r0 + 128;
        const float2 a0 = ((const float2*)r0)[lane];
        const float2 a1 = ((const float2*)r1)[lane];
        float2* R = pool + rs * 128;            // cur=0 slot for this wave
        R[2 * lane] = make_float2(a0.x, a1.x);
        R[2 * lane + 1] = make_float2(a0.y, a1.y);
        __syncthreads();  // tw visible (row data is wave-local already)
        int cur = 0, m = 1;
        for (int l = 64; l >= 1; l >>= 1) {   // 7 stages, barrier-free
            float2* Bc = pool + cur * 512 + rs * 128;
            float2* Bn = pool + (cur ^ 1) * 512 + rs * 128;
            const int k = lane & (m - 1);
            const float2 w = tw[lane - k];
            float2 a = Bc[lane];
            float2 b = Bc[lane + 64];
            float2 d = csub(a, b);
            const int o = 2 * lane - k;
            Bn[o] = cadd(a, b);
            Bn[o + m] = cmul(w, d);
            cur ^= 1;
            m <<= 1;
        }
        float2* Bc = pool + cur * 512 + rs * 128;
        float2* d0 = Fx + (size_t)gpair * 256;
        float2* d1 = d0 + 128;
        for (int h = 0; h < 2; ++h) {
            int tt = lane + h * 64;
            if (tt > 64) continue;  // Hermitian: cols 65..127 rebuilt in k6
            float2 Zt = Bc[tt];
            float2 Zm = Bc[(128 - tt) & 127];
            d0[tt] = make_float2(0.5f * (Zt.x + Zm.x), 0.5f * (Zt.y - Zm.y));
            float ax = Zt.x - Zm.x, ay = Zt.y + Zm.y;
            d1[tt] = make_float2(0.5f * ay, -0.5f * ax);
        }
    } else {
        float2* tw = pool + 2048;  // 128 entries, e^{-i pi k/128}
        for (int i = tid; i < 128; i += 256) {
            float s, c;
            __sincosf(-(float)M_PI * (float)i / 128.f, &s, &c);
            tw[i] = make_float2(c, s);
        }
        const int b3 = blockIdx.x - 4096;
        const int img = b3 / 7;
        const int sub = b3 % 7;
        int lr = sub * 4 + rs;
        const bool live = (lr < 25);
        if (!live) lr = 24;  // dead wave computes garbage, no store
        const float* krow = kin + img * 625 + lr * 25;
        float2* R = pool + rs * 256;
#pragma unroll
        for (int h = 0; h < 4; ++h) {
            int v = lane + h * 64;
            int pc = (v + 12) & 255;
            R[v] = make_float2(pc < 25 ? krow[pc] : 0.f, 0.f);
        }
        __syncthreads();  // tw visible
        int cur = 0, m = 1;
        for (int l = 128; l >= 1; l >>= 1) {  // 8 stages, barrier-free
            float2* Bc = pool + cur * 1024 + rs * 256;
            float2* Bn = pool + (cur ^ 1) * 1024 + rs * 256;
#pragma unroll
            for (int b = 0; b < 2; ++b) {
                const int bt = lane + 64 * b;
                const int k = bt & (m - 1);
                const float2 w = tw[bt - k];
                float2 a = Bc[bt];
                float2 bb = Bc[bt + 128];
                float2 d = csub(a, bb);
                const int o = 2 * bt - k;
                Bn[o] = cadd(a, bb);
                Bn[o + m] = cmul(w, d);
            }
            cur ^= 1;
            m <<= 1;
        }
        if (live) {
            float2* Bc = pool + cur * 1024 + rs * 256;
            float2* dst = FBtmp + (size_t)img * 6400 + lr * 256;
#pragma unroll
            for (int h = 0; h < 4; ++h) {
                int v = lane + h * 64;
                dst[v] = Bc[v];
            }
        }
    }
}

// K2: column FFT of Fx, in place, cols 0..64 only -> 5 tiles of 16.
// R17: in-place single-buffer -> 17.4 KB LDS -> 8 blocks/CU.
__global__ __launch_bounds__(256) void k2_fft_cols_x(float2* __restrict__ Fx) {
    __shared__ float2 buf[16][130];
    __shared__ float2 tw[96];
    const int tid = threadIdx.x;
    const int img = blockIdx.x / 5;
    const int c0 = (blockIdx.x % 5) * 16;
    for (int i = tid; i < 96; i += 256) {
        float s, c;
        __sincosf(-(float)M_PI * (float)i / 64.f, &s, &c);
        tw[i] = make_float2(c, s);
    }
    float2* base = Fx + (size_t)img * 16384 + c0;
    for (int it = 0; it < 8; ++it) {
        int idx = it * 256 + tid;
        int rr = idx >> 4, cc = idx & 15;
        buf[cc][rr] = base[rr * 128 + cc];
    }
    __syncthreads();
    fft4_cols_inplace<-1, 16>(buf, tw);
    __syncthreads();
    for (int it = 0; it < 8; ++it) {
        int idx = it * 256 + tid;
        int rr = idx >> 4, cc = idx & 15;
        base[rr * 128 + cc] = buf[cc][rr];
    }
}

// K6: fused column-DFT + M + FX build + radix-4 row IFFT + Hermitian fold.
// Block = (img, p-pair {pa=2b, pb=2b+1}); wave rs owns one of 4 rows.
// R17: Fx/alpha loads hoisted above the DFT (latency hidden under FMAs).
__global__ __launch_bounds__(256, 4) void k6_fused(const float2* __restrict__ FBtmp,
                                                   const float2* __restrict__ Fx,
                                                   const float* __restrict__ alpha,
                                                   float2* __restrict__ Zf) {
    __shared__ __align__(16) float2 sm_buf0[4 * 288];  // per-wave Tt; FFT buf A
    __shared__ __align__(16) float2 sm_buf1[4 * 288];  // stage overlay; FFT buf B
    __shared__ float2 tw[192];                         // e^{+i pi k/128}, k<192
    float2* stageF = sm_buf1;            // [4][256] flat
    const int tid = threadIdx.x;
    const int rs = tid >> 6;             // row slot = wave id
    const int q = tid & 63;
    const int img = blockIdx.x / 33;
    const int bq = blockIdx.x % 33;
    const int pa = 2 * bq;
    const int pb = (pa + 1 < 65) ? (pa + 1) : 64;   // last block: pb==pa==64

    const float2* src = FBtmp + (size_t)img * 6400 + tid;
    float2 S[25];
#pragma unroll
    for (int p = 0; p < 25; ++p) S[p] = src[p * 256];

    // Hoisted row indices (pure arithmetic) + global loads (R17).
    const int p = (rs < 2) ? pa : pb;
    const int sb = rs & 2;
    const int u = ((rs & 1) == 0) ? p : (128 - p);   // 0..128
    const int um = u & 127;
    const int msel = (um == p) ? 0 : 1;
    const int mi = sb | msel;
    const int oi = sb | (1 - msel);
    float2 fxA = Fx[(size_t)img * 16384 + um * 128 + q];          // t=q (<=63)
    float2 fxB;
    {
        const int t = q + 64;
        const bool mir = (t > 64);      // false only at q==0 (t==64)
        const int rr = mir ? ((128 - um) & 127) : um;
        const int cc = mir ? (128 - t) : t;
        fxB = Fx[(size_t)img * 16384 + rr * 128 + cc];
        if (mir) fxB.y = -fxB.y;
    }
    const float b4 = 4.f / (1.f + __expf(9.f - alpha[img & 63])) + 4e-3f;  // 4b

    for (int i = tid; i < 192; i += 256) {
        float s, c;
        __sincosf((float)M_PI * (float)i / 128.f, &s, &c);
        tw[i] = make_float2(c, s);
    }
    // Per-wave DFT twiddles (R16): wave rs fills its OWN 50-entry copy.
    float2* Ttw = sm_buf0 + rs * 288;
    if (q < 50) {
        const int which = q >= 25;
        const int pp = which ? (q - 25) : q;
        const int uu = which ? pb : pa;
        const float k2pi = -2.f * (float)M_PI / 256.f;
        float s, c;
        __sincosf(k2pi * (float)((uu * (pp + 244)) & 255), &s, &c);
        Ttw[q] = make_float2(c, s);
    }

    // R15: parity-split FMA DFT. Per tap: 8 FMAs. Mirror recombination once.
    {
        float AExx = 0.f, AEyy = 0.f, AExy = 0.f, AEyx = 0.f;
        float AOxx = 0.f, AOyy = 0.f, AOxy = 0.f, AOyx = 0.f;
        float BExx = 0.f, BEyy = 0.f, BExy = 0.f, BEyx = 0.f;
        float BOxx = 0.f, BOyy = 0.f, BOxy = 0.f, BOyx = 0.f;
#pragma unroll
        for (int pp = 0; pp < 25; ++pp) {
            const float2 s = S[pp];
            const float2 ta = Ttw[pp];
            const float2 tb = Ttw[25 + pp];
            if ((pp & 1) == 0) {
                AExx = fmaf(ta.x, s.x, AExx);
                AEyy = fmaf(ta.y, s.y, AEyy);
                AExy = fmaf(ta.x, s.y, AExy);
                AEyx = fmaf(ta.y, s.x, AEyx);
                BExx = fmaf(tb.x, s.x, BExx);
                BEyy = fmaf(tb.y, s.y, BEyy);
                BExy = fmaf(tb.x, s.y, BExy);
                BEyx = fmaf(tb.y, s.x, BEyx);
            } else {
                AOxx = fmaf(ta.x, s.x, AOxx);
                AOyy = fmaf(ta.y, s.y, AOyy);
                AOxy = fmaf(ta.x, s.y, AOxy);
                AOyx = fmaf(ta.y, s.x, AOyx);
                BOxx = fmaf(tb.x, s.x, BOxx);
                BOyy = fmaf(tb.y, s.y, BOyy);
                BOxy = fmaf(tb.x, s.y, BOxy);
                BOyx = fmaf(tb.y, s.x, BOyx);
            }
        }
        stageF[tid] = make_float2((AExx + AOxx) - (AEyy + AOyy),
                                  (AExy + AOxy) + (AEyx + AOyx));
        stageF[256 + tid] = make_float2((AExx - AOxx) + (AEyy - AOyy),
                                        (AExy - AOxy) - (AEyx - AOyx));
        stageF[512 + tid] = make_float2((BExx + BOxx) - (BEyy + BOyy),
                                        (BExy + BOxy) + (BEyx + BOyx));
        stageF[768 + tid] = make_float2((BExx - BOxx) + (BEyy - BOyy),
                                        (BExy - BOxy) - (BEyx - BOyx));
    }
    __syncthreads();  // B1: stage + tw visible

    const float ci = tw[um].x, si = -tw[um].y;
    const float scale = 1.f / 65536.f;
    const float2 Di0 = make_float2(1.f + ci, si);
    const float2 Di1 = make_float2(1.f - ci, -si);
    const float2 Du = (u < 128) ? Di0 : Di1;
    float2 X0, X1, X2, X3;  // FX at cols q, q+64, q+128, q+192
#pragma unroll
    for (int h = 0; h < 2; ++h) {
        const int t = q + 64 * h;        // 0..127
        float2 f00 = stageF[mi * 256 + t];
        float2 f01 = stageF[mi * 256 + t + 128];
        float2 f10, f11;
        if (um == 0) {
            f10 = stageF[oi * 256 + t];
            f11 = stageF[oi * 256 + t + 128];
        } else {
            f10 = conjf2(stageF[oi * 256 + ((256 - t) & 255)]);
            f11 = conjf2(stageF[oi * 256 + 128 - t]);
        }
        float2 fx = (h == 0) ? fxA : fxB;
        const float cj = tw[t].x, sj = -tw[t].y;
        float2 Dj0 = make_float2(1.f + cj, sj);
        float2 Dj1 = make_float2(1.f - cj, -sj);
        // S1' = 4*S1, S2' = 4*S2; mm = (4 - S1')/(S2' + 4b)  (R16 algebra)
        float2 A = cadd(cmul(f00, Dj0), cmul(f01, Dj1));
        float2 Bt = cadd(cmul(f10, Dj0), cmul(f11, Dj1));
        float2 S1 = cadd(cmul(A, Di0), cmul(Bt, Di1));
        float S2 = f00.x * f00.x + f00.y * f00.y + f01.x * f01.x + f01.y * f01.y +
                   f10.x * f10.x + f10.y * f10.y + f11.x * f11.x + f11.y * f11.y;
        float inv = 1.f / (S2 + b4);
        float2 mm = make_float2((4.f - S1.x) * inv, (-S1.y) * inv);
        float2 c0v = (u < 128) ? f00 : f10;
        float2 c1v = (u < 128) ? f01 : f11;
        float2 t0 = cadd(cmul(conjf2(c0v), mm), cmul(Du, Dj0));
        float2 t1 = cadd(cmul(conjf2(c1v), mm), cmul(Du, Dj1));
        float2 FX0 = cmul(fx, t0);
        float2 FX1 = cmul(fx, t1);
        FX0.x *= scale; FX0.y *= scale;
        FX1.x *= scale; FX1.y *= scale;
        if (h == 0) { X0 = FX0; X2 = FX1; } else { X1 = FX0; X3 = FX1; }
    }

    // FFT stage m=1 in regs (jm=q, k=0): outputs at 4q..4q+3 -> 2x b128.
    {
        float2 s02 = cadd(X0, X2), d02 = csub(X0, X2);
        float2 s13 = cadd(X1, X3), d13 = csub(X1, X3);
        float2 b0 = cadd(s02, s13), b2v = csub(s02, s13);
        float2 b1 = make_float2(d02.x - d13.y, d02.y + d13.x);
        float2 b3 = make_float2(d02.x + d13.y, d02.y - d13.x);
        float2 c1 = cmul(tw[q], b1);
        float2 c2 = cmul(tw[2 * q], b2v);
        float2 c3 = cmul(tw[3 * q], b3);
        float4* dst4 = reinterpret_cast<float4*>(&sm_buf0[rs * 288 + PHI16(4 * q)]);
        dst4[0] = make_float4(b0.x, b0.y, c1.x, c1.y);
        dst4[1] = make_float4(c2.x, c2.y, c3.x, c3.y);
    }
    __syncthreads();  // B2: all stage (buf1) reads done before m=4 writes buf1

    // stage m=4: buf0 -> buf1 (wave-local)
    {
        const int k4 = q & 3, jm = q - k4;
        float2 a0 = sm_buf0[rs * 288 + PHI16(q)];
        float2 a1 = sm_buf0[rs * 288 + PHI16(q + 64)];
        float2 a2 = sm_buf0[rs * 288 + PHI16(q + 128)];
        float2 a3 = sm_buf0[rs * 288 + PHI16(q + 192)];
        float2 s02 = cadd(a0, a2), d02 = csub(a0, a2);
        float2 s13 = cadd(a1, a3), d13 = csub(a1, a3);
        float2 b0 = cadd(s02, s13), b2v = csub(s02, s13);
        float2 b1 = make_float2(d02.x - d13.y, d02.y + d13.x);
        float2 b3 = make_float2(d02.x + d13.y, d02.y - d13.x);
        const int o = 4 * jm + k4;
        sm_buf1[rs * 288 + PHI16(o)] = b0;
        sm_buf1[rs * 288 + PHI16(o + 4)] = cmul(tw[jm], b1);
        sm_buf1[rs * 288 + PHI16(o + 8)] = cmul(tw[2 * jm], b2v);
        sm_buf1[rs * 288 + PHI16(o + 12)] = cmul(tw[3 * jm], b3);
    }
    // stage m=16: buf1 -> buf0 (wave-local, in-order DS)
    {
        const int k16 = q & 15, jm = q - k16;
        float2 a0 = sm_buf1[rs * 288 + PHI16(q)];
        float2 a1 = sm_buf1[rs * 288 + PHI16(q + 64)];
        float2 a2 = sm_buf1[rs * 288 + PHI16(q + 128)];
        float2 a3 = sm_buf1[rs * 288 + PHI16(q + 192)];
        float2 s02 = cadd(a0, a2), d02 = csub(a0, a2);
        float2 s13 = cadd(a1, a3), d13 = csub(a1, a3);
        float2 b0 = cadd(s02, s13), b2v = csub(s02, s13);
        float2 b1 = make_float2(d02.x - d13.y, d02.y + d13.x);
        float2 b3 = make_float2(d02.x + d13.y, d02.y - d13.x);
        const int o = 4 * jm + k16;
        sm_buf0[rs * 288 + PHI16(o)] = b0;
        sm_buf0[rs * 288 + PHI16(o + 16)] = cmul(tw[jm], b1);
        sm_buf0[rs * 288 + PHI16(o + 32)] = cmul(tw[2 * jm], b2v);
        sm_buf0[rs * 288 + PHI16(o + 48)] = cmul(tw[3 * jm], b3);
    }
    // stage m=64 (jm=0, w=1) in regs: outputs at {q, q+64, q+128, q+192}.
    float2 Y0, Y1, Y2, Y3;
    {
        float2 a0 = sm_buf0[rs * 288 + PHI16(q)];
        float2 a1 = sm_buf0[rs * 288 + PHI16(q + 64)];
        float2 a2 = sm_buf0[rs * 288 + PHI16(q + 128)];
        float2 a3 = sm_buf0[rs * 288 + PHI16(q + 192)];
        float2 s02 = cadd(a0, a2), d02 = csub(a0, a2);
        float2 s13 = cadd(a1, a3), d13 = csub(a1, a3);
        Y0 = cadd(s02, s13);
        Y1 = make_float2(d02.x - d13.y, d02.y + d13.x);
        Y2 = csub(s02, s13);
        Y3 = make_float2(d02.x + d13.y, d02.y - d13.x);
    }
    // partner exchange for the fold (buf1 rs-region free after m=16 reads)
    sm_buf1[rs * 288 + PHI16(q)] = Y0;
    sm_buf1[rs * 288 + PHI16(q + 64)] = Y1;
    sm_buf1[rs * 288 + PHI16(q + 128)] = Y2;
    sm_buf1[rs * 288 + PHI16(q + 192)] = Y3;
    __syncthreads();  // B3: cross-wave fold reads rs^1

    // Hermitian fold: Zf[u0] = e + i*w.o, own values in regs, partner via LDS.
    const int u0 = u;
    bool dowrite = ((rs & 1) == 0) ? true : (p > 0 && p < 64);
    if (pb == pa && rs >= 2) dowrite = false;  // last-block dedup
    if (dowrite) {
        const float2 w = tw[u0];
        float2* zb = Zf + (size_t)img * 32768 + (size_t)u0 * 256;
        float2 own[4] = {Y0, Y1, Y2, Y3};
#pragma unroll
        for (int hh = 0; hh < 4; ++hh) {
            const int jj = q + 64 * hh;
            float2 su = own[hh];
            float2 s2 = sm_buf1[(rs ^ 1) * 288 + PHI16(jj)];
            float2 e = make_float2(su.x + s2.x, su.y - s2.y);   // su + conj(s2)
            float2 o_ = make_float2(su.x - s2.x, su.y + s2.y);  // su - conj(s2)
            float2 wo = cmul(w, o_);
            zb[jj] = make_float2(e.x - wo.y, e.y + wo.x);       // e + i*wo
        }
    }
}

// K7: pure C2R column IFFT, 16 cols/block, in-place radix-4 (R17).
__global__ __launch_bounds__(256) void k7_c2r(const float2* __restrict__ Zf,
                                              float* __restrict__ out) {
    __shared__ float2 buf[16][130];
    __shared__ float2 tw[96];  // e^{+i pi k/64}
    const int tid = threadIdx.x;
    const int img = blockIdx.x >> 4;
    const int c0 = (blockIdx.x & 15) * 16;
    for (int i = tid; i < 96; i += 256) {
        float s, c;
        __sincosf((float)M_PI * (float)i / 64.f, &s, &c);
        tw[i] = make_float2(c, s);
    }
    const float2* zb = Zf + (size_t)img * 32768 + c0;
    for (int it = 0; it < 8; ++it) {
        int idx = it * 256 + tid;
        int rr = idx >> 4, cc = idx & 15;
        buf[cc][rr] = zb[rr * 256 + cc];
    }
    __syncthreads();
    fft4_cols_inplace<1, 16>(buf, tw);
    __syncthreads();
    float* ob = out + (size_t)img * 65536 + c0;
    for (int it = 0; it < 8; ++it) {
        int idx = it * 256 + tid;
        int n = idx >> 4, c = idx & 15;
        float2 y = buf[c][n];
        ob[(2 * n) * 256 + c] = y.x;
        ob[(2 * n + 1) * 256 + c] = y.y;
    }
}

extern "C" void kernel_launch(void* const* d_in, const int* in_sizes, int n_in,
                              void* d_out, int out_size, void* d_ws, size_t ws_size,
                              hipStream_t stream) {
    const float* x = (const float*)d_in[0];      // (4,64,128,128)
    const float* k = (const float*)d_in[1];      // (4,64,25,25)
    const float* alpha = (const float*)d_in[2];  // (1,64,1,1)
    float* out = (float*)d_out;                  // (4,64,256,256)

    float2* Fx = (float2*)d_ws;           // 256*16384   = 32 MB (cols 0..64 live)
    float2* Zf = Fx + 256 * 16384;        // 256*128*256 = 64 MB (folded)
    float2* FBtmp = Zf + 256 * 32768;     // 256*25*256  = 13.1 MB

    hipLaunchKernelGGL(k13, dim3(4096 + 256 * 7), dim3(256), 0, stream, x, k, Fx, FBtmp);
    hipLaunchKernelGGL(k2_fft_cols_x, dim3(256 * 5), dim3(256), 0, stream, Fx);
    hipLaunchKernelGGL(k6_fused, dim3(256 * 33), dim3(256), 0, stream, FBtmp, Fx, alpha, Zf);
    hipLaunchKernelGGL(k7_c2r, dim3(4096), dim3(256), 0, stream, Zf, out);
}